// Round 1
// baseline (737.660 us; speedup 1.0000x reference)
//
#include <hip/hip_runtime.h>
#include <math.h>

#define D 128
#define NCLS 32
#define TSLOT 16
#define RB 128

// ---------------- zero counters ----------------
__global__ void zero_k(int* hist, int* cursor) {
  int t = threadIdx.x;
  if (t < NCLS) { hist[t] = 0; cursor[t] = 0; }
}

// ---------------- label histogram ----------------
__global__ void hist_k(const int* __restrict__ label, int M, int* __restrict__ hist) {
  __shared__ int h[NCLS];
  if (threadIdx.x < NCLS) h[threadIdx.x] = 0;
  __syncthreads();
  int stride = gridDim.x * blockDim.x;
  for (int i = blockIdx.x * blockDim.x + threadIdx.x; i < M; i += stride)
    atomicAdd(&h[label[i]], 1);
  __syncthreads();
  if (threadIdx.x < NCLS) atomicAdd(&hist[threadIdx.x], h[threadIdx.x]);
}

// ---------------- exclusive prefix ----------------
__global__ void prefix_k(const int* __restrict__ hist, int* __restrict__ cstart,
                         int* __restrict__ cursor) {
  if (threadIdx.x == 0) {
    int run = 0;
    for (int j = 0; j < NCLS; ++j) { cstart[j] = run; cursor[j] = run; run += hist[j]; }
    cstart[NCLS] = run;
  }
}

// ---------------- scatter row indices into class segments ----------------
__global__ void scatter_k(const int* __restrict__ label, int M, int* cursor,
                          int* __restrict__ idxbuf) {
  int stride = gridDim.x * blockDim.x;
  for (int i = blockIdx.x * blockDim.x + threadIdx.x; i < M; i += stride) {
    int j = label[i];
    int p = atomicAdd(&cursor[j], 1);
    idxbuf[p] = i;
  }
}

// ---------------- per-class Gram accumulation ----------------
// grid = NCLS*TSLOT blocks, 256 threads; block (cls,slot) grid-strides over RB-row
// chunks of its class segment; 8x8 fp32 register tile per thread (16x16 threads).
__global__ __launch_bounds__(256) void cov_k(const float* __restrict__ Z,
                                             const int* __restrict__ idxbuf,
                                             const int* __restrict__ hist,
                                             const int* __restrict__ cstart,
                                             float* __restrict__ partials) {
  __shared__ float zs[32][D];
  const int b = blockIdx.x;
  const int cls = b / TSLOT, slot = b % TSLOT;
  const int tid = threadIdx.x;
  const int tr = tid >> 4, tc = tid & 15;
  const int R = tr * 8, C = tc * 8;

  const int mj = hist[cls];
  const int seg0 = cstart[cls];
  const int segend = seg0 + mj;
  const int nch = (mj + RB - 1) / RB;

  float acc[8][8];
#pragma unroll
  for (int r = 0; r < 8; ++r)
#pragma unroll
    for (int c = 0; c < 8; ++c) acc[r][c] = 0.f;

  for (int ch = slot; ch < nch; ch += TSLOT) {
    int r0 = seg0 + ch * RB;
    int r1 = min(r0 + RB, segend);
    for (int s = r0; s < r1; s += 32) {
      __syncthreads();  // previous stage's reads of zs done
#pragma unroll
      for (int l = 0; l < 4; ++l) {
        int flat = l * 256 + tid;
        int row = flat >> 5, c4 = flat & 31;
        float4 v = make_float4(0.f, 0.f, 0.f, 0.f);
        int gr = s + row;
        if (gr < r1) {
          int ridx = idxbuf[gr];
          v = *(const float4*)(Z + (size_t)ridx * D + (c4 << 2));
        }
        *(float4*)&zs[row][c4 << 2] = v;  // zero-padded tail rows
      }
      __syncthreads();
#pragma unroll
      for (int kk = 0; kk < 32; ++kk) {
        const float* zk = &zs[kk][0];
        float4 x0 = *(const float4*)&zk[R];
        float4 x1 = *(const float4*)&zk[R + 4];
        float4 y0 = *(const float4*)&zk[C];
        float4 y1 = *(const float4*)&zk[C + 4];
        float xr[8] = {x0.x, x0.y, x0.z, x0.w, x1.x, x1.y, x1.z, x1.w};
        float yc[8] = {y0.x, y0.y, y0.z, y0.w, y1.x, y1.y, y1.z, y1.w};
#pragma unroll
        for (int r = 0; r < 8; ++r)
#pragma unroll
          for (int c = 0; c < 8; ++c) acc[r][c] = fmaf(xr[r], yc[c], acc[r][c]);
      }
    }
  }

  // every block writes its full partial (zeros if it had no chunks) -> deterministic reduce
  size_t base = (size_t)b * (D * D);
#pragma unroll
  for (int r = 0; r < 8; ++r) {
    float4 w0 = make_float4(acc[r][0], acc[r][1], acc[r][2], acc[r][3]);
    float4 w1 = make_float4(acc[r][4], acc[r][5], acc[r][6], acc[r][7]);
    *(float4*)&partials[base + (size_t)(R + r) * D + C] = w0;
    *(float4*)&partials[base + (size_t)(R + r) * D + C + 4] = w1;
  }
}

// ---------------- reduce partials -> 32 class covs + total cov ----------------
__global__ void reduce_k(const float* __restrict__ partials, float* __restrict__ covs) {
  int e = blockIdx.x * blockDim.x + threadIdx.x;  // 0..D*D-1
  double tot = 0.0;
  for (int j = 0; j < NCLS; ++j) {
    double s = 0.0;
    for (int t = 0; t < TSLOT; ++t)
      s += (double)partials[(size_t)(j * TSLOT + t) * (D * D) + e];
    covs[(size_t)j * (D * D) + e] = (float)s;
    tot += s;
  }
  covs[(size_t)NCLS * (D * D) + e] = (float)tot;
}

// ---------------- register-resident Cholesky logdet (one matrix per block) ----
__global__ __launch_bounds__(256) void chol_k(const float* __restrict__ covs,
                                              const int* __restrict__ hist,
                                              int Mtot, double* __restrict__ results) {
  __shared__ float raw[D];
  __shared__ float colL[D];
  __shared__ double red[256];
  const int j = blockIdx.x;
  const float* A = covs + (size_t)j * (D * D);
  const int tid = threadIdx.x;
  const int tr = tid >> 4, tc = tid & 15;
  const int R = tr * 8, C = tc * 8;

  float a[8][8];
#pragma unroll
  for (int r = 0; r < 8; ++r) {
    float4 v0 = *(const float4*)&A[(size_t)(R + r) * D + C];
    float4 v1 = *(const float4*)&A[(size_t)(R + r) * D + C + 4];
    a[r][0] = v0.x; a[r][1] = v0.y; a[r][2] = v0.z; a[r][3] = v0.w;
    a[r][4] = v1.x; a[r][5] = v1.y; a[r][6] = v1.z; a[r][7] = v1.w;
  }

  double ld = 0.0;
  for (int k = 0; k < D; ++k) {
    // stage 1: owners of column k publish raw column (static reg indices via unrolled match)
    if (tc == (k >> 3)) {
      const int kc = k & 7;
#pragma unroll
      for (int q = 0; q < 8; ++q)
        if (q == kc) {
#pragma unroll
          for (int r = 0; r < 8; ++r) raw[R + r] = a[r][q];
        }
    }
    __syncthreads();
    // stage 2: normalize sub-column; zero elsewhere so the rank-1 update self-masks
    if (tid < D) {
      float piv = raw[k];
      if (tid == k) ld += log((double)piv);
      float inv = 1.0f / sqrtf(fmaxf(piv, 1e-30f));
      colL[tid] = (tid > k) ? raw[tid] * inv : 0.f;
    }
    __syncthreads();
    // stage 3: rank-1 update of register tiles
    float4 cr0 = *(const float4*)&colL[R];
    float4 cr1 = *(const float4*)&colL[R + 4];
    float4 cc0 = *(const float4*)&colL[C];
    float4 cc1 = *(const float4*)&colL[C + 4];
    float xr[8] = {cr0.x, cr0.y, cr0.z, cr0.w, cr1.x, cr1.y, cr1.z, cr1.w};
    float yc[8] = {cc0.x, cc0.y, cc0.z, cc0.w, cc1.x, cc1.y, cc1.z, cc1.w};
#pragma unroll
    for (int r = 0; r < 8; ++r)
#pragma unroll
      for (int c = 0; c < 8; ++c) a[r][c] = fmaf(-xr[r], yc[c], a[r][c]);
  }

  red[tid] = ld;
  __syncthreads();
  for (int off = 128; off > 0; off >>= 1) {
    if (tid < off) red[tid] += red[tid + off];
    __syncthreads();
  }
  if (tid == 0) {
    double lsum = red[0];
    if (j < NCLS) {
      int mj = hist[j];
      double res = 0.0;
      if (mj > 0) {
        double cj = (double)D / ((double)mj * 0.01);
        res = ((double)D * log(cj) + lsum) * (double)mj / (2.0 * (double)Mtot);
      }
      results[j] = res;
    } else {
      double c = (double)D / ((double)Mtot * 0.01);
      results[NCLS] = ((double)D * log(c) + lsum) * 0.5;
    }
  }
}

// ---------------- combine ----------------
__global__ void final_k(const double* __restrict__ results, float* __restrict__ out) {
  if (threadIdx.x == 0 && blockIdx.x == 0) {
    double s = 0.0;
    for (int j = 0; j < NCLS; ++j) s += results[j];
    out[0] = (float)(s - results[NCLS]);
  }
}

extern "C" void kernel_launch(void* const* d_in, const int* in_sizes, int n_in,
                              void* d_out, int out_size, void* d_ws, size_t ws_size,
                              hipStream_t stream) {
  const float* Z = (const float*)d_in[0];
  const int* label = (const int*)d_in[1];
  const int Mtot = in_sizes[1];
  float* out = (float*)d_out;

  // ws layout (bytes):
  //   0    : int hist[32]
  //   128  : int cursor[32]
  //   256  : int cstart[33]
  //   512  : double results[33]
  //   1024 : int idxbuf[M]
  //   then : float partials[NCLS*TSLOT][D*D]   (32 MiB)
  //   then : float covs[NCLS+1][D*D]           (~2.1 MiB)
  char* ws = (char*)d_ws;
  int* hist = (int*)(ws + 0);
  int* cursor = (int*)(ws + 128);
  int* cstart = (int*)(ws + 256);
  double* results = (double*)(ws + 512);
  int* idxbuf = (int*)(ws + 1024);
  float* partials = (float*)(ws + 1024 + (size_t)Mtot * sizeof(int));
  float* covs = partials + (size_t)NCLS * TSLOT * D * D;

  zero_k<<<1, 64, 0, stream>>>(hist, cursor);
  hist_k<<<256, 256, 0, stream>>>(label, Mtot, hist);
  prefix_k<<<1, 64, 0, stream>>>(hist, cstart, cursor);
  scatter_k<<<256, 256, 0, stream>>>(label, Mtot, cursor, idxbuf);
  cov_k<<<NCLS * TSLOT, 256, 0, stream>>>(Z, idxbuf, hist, cstart, partials);
  reduce_k<<<(D * D) / 256, 256, 0, stream>>>(partials, covs);
  chol_k<<<NCLS + 1, 256, 0, stream>>>(covs, hist, Mtot, results);
  final_k<<<1, 64, 0, stream>>>(results, out);
}

// Round 2
// 275.487 us; speedup vs baseline: 2.6777x; 2.6777x over previous
//
#include <hip/hip_runtime.h>
#include <math.h>

#define D 128
#define NCLS 32
#define TSLOT 16
#define RB 128
#define CHUNK 256  // labels per sort block

// ---------------- zero counters ----------------
__global__ void zero_k(int* hist) {
  int t = threadIdx.x;
  if (t < NCLS) hist[t] = 0;
}

// ---------------- per-block label histogram (+ global hist) ----------------
__global__ __launch_bounds__(64) void hist_blk_k(const int* __restrict__ label, int M,
                                                 int NB, int* __restrict__ blkhist_t,
                                                 int* __restrict__ hist) {
  __shared__ int h[NCLS];
  const int lane = threadIdx.x;
  const int b = blockIdx.x;
  if (lane < NCLS) h[lane] = 0;
  __syncthreads();
  const int s0 = b * CHUNK;
#pragma unroll
  for (int it = 0; it < CHUNK / 64; ++it) {
    int i = s0 + it * 64 + lane;
    if (i < M) atomicAdd(&h[label[i]], 1);
  }
  __syncthreads();
  if (lane < NCLS) {
    blkhist_t[lane * NB + b] = h[lane];
    atomicAdd(&hist[lane], h[lane]);
  }
}

// ---------------- exclusive prefix over classes ----------------
__global__ void prefix_k(const int* __restrict__ hist, int* __restrict__ cstart) {
  if (threadIdx.x == 0) {
    int run = 0;
    for (int j = 0; j < NCLS; ++j) { cstart[j] = run; run += hist[j]; }
    cstart[NCLS] = run;
  }
}

// ---------------- per-class scan over blocks: base_t[j][b] ----------------
__global__ __launch_bounds__(64) void base_k(const int* __restrict__ blkhist_t,
                                             const int* __restrict__ cstart, int NB,
                                             int* __restrict__ base_t) {
  const int j = blockIdx.x;
  const int lane = threadIdx.x;
  const int K = (NB + 63) / 64;  // contiguous vals per lane
  int vals[32];                   // K <= 32 for M <= 512K
  int run = 0;
  for (int k = 0; k < K; ++k) {
    int b = lane * K + k;
    int v = (b < NB) ? blkhist_t[j * NB + b] : 0;
    vals[k] = v;
    run += v;
  }
  int incl = run;
  for (int off = 1; off < 64; off <<= 1) {
    int o = __shfl_up(incl, off);
    if (lane >= off) incl += o;
  }
  int pos = cstart[j] + (incl - run);  // exclusive
  for (int k = 0; k < K; ++k) {
    int b = lane * K + k;
    if (b < NB) base_t[j * NB + b] = pos;
    pos += vals[k];
  }
}

// ---------------- stable, atomic-free scatter (1 wave / block) ----------------
__global__ __launch_bounds__(64) void scatter2_k(const int* __restrict__ label, int M,
                                                 int NB, const int* __restrict__ base_t,
                                                 int* __restrict__ idxbuf) {
  __shared__ int cur[NCLS];
  const int b = blockIdx.x;
  const int lane = threadIdx.x;
  if (lane < NCLS) cur[lane] = base_t[lane * NB + b];
  __syncthreads();
  const int s0 = b * CHUNK;
#pragma unroll
  for (int it = 0; it < CHUNK / 64; ++it) {
    int i = s0 + it * 64 + lane;
    int j = (i < M) ? label[i] : -1;
    unsigned long long mask = 0;
#pragma unroll
    for (int q = 0; q < NCLS; ++q) {
      unsigned long long mm = __ballot(j == q);
      if (j == q) mask = mm;
    }
    if (j >= 0) {
      int myoff = __popcll(mask & ((1ull << lane) - 1ull));
      int basec = cur[j];
      idxbuf[basec + myoff] = i;
      if (myoff == 0) cur[j] = basec + __popcll(mask);  // per-class leader, in-order wave
    }
    __syncthreads();
  }
}

// ---------------- per-class Gram accumulation ----------------
__global__ __launch_bounds__(256) void cov_k(const float* __restrict__ Z,
                                             const int* __restrict__ idxbuf,
                                             const int* __restrict__ hist,
                                             const int* __restrict__ cstart,
                                             float* __restrict__ partials) {
  __shared__ float zs[32][D];
  const int b = blockIdx.x;
  const int cls = b / TSLOT, slot = b % TSLOT;
  const int tid = threadIdx.x;
  const int tr = tid >> 4, tc = tid & 15;
  const int R = tr * 8, C = tc * 8;

  const int mj = hist[cls];
  const int seg0 = cstart[cls];
  const int segend = seg0 + mj;
  const int nch = (mj + RB - 1) / RB;

  float acc[8][8];
#pragma unroll
  for (int r = 0; r < 8; ++r)
#pragma unroll
    for (int c = 0; c < 8; ++c) acc[r][c] = 0.f;

  for (int ch = slot; ch < nch; ch += TSLOT) {
    int r0 = seg0 + ch * RB;
    int r1 = min(r0 + RB, segend);
    for (int s = r0; s < r1; s += 32) {
      __syncthreads();  // previous stage's reads of zs done
#pragma unroll
      for (int l = 0; l < 4; ++l) {
        int flat = l * 256 + tid;
        int row = flat >> 5, c4 = flat & 31;
        float4 v = make_float4(0.f, 0.f, 0.f, 0.f);
        int gr = s + row;
        if (gr < r1) {
          int ridx = idxbuf[gr];
          v = *(const float4*)(Z + (size_t)ridx * D + (c4 << 2));
        }
        *(float4*)&zs[row][c4 << 2] = v;  // zero-padded tail rows
      }
      __syncthreads();
#pragma unroll
      for (int kk = 0; kk < 32; ++kk) {
        const float* zk = &zs[kk][0];
        float4 x0 = *(const float4*)&zk[R];
        float4 x1 = *(const float4*)&zk[R + 4];
        float4 y0 = *(const float4*)&zk[C];
        float4 y1 = *(const float4*)&zk[C + 4];
        float xr[8] = {x0.x, x0.y, x0.z, x0.w, x1.x, x1.y, x1.z, x1.w};
        float yc[8] = {y0.x, y0.y, y0.z, y0.w, y1.x, y1.y, y1.z, y1.w};
#pragma unroll
        for (int r = 0; r < 8; ++r)
#pragma unroll
          for (int c = 0; c < 8; ++c) acc[r][c] = fmaf(xr[r], yc[c], acc[r][c]);
      }
    }
  }

  size_t base = (size_t)b * (D * D);
#pragma unroll
  for (int r = 0; r < 8; ++r) {
    float4 w0 = make_float4(acc[r][0], acc[r][1], acc[r][2], acc[r][3]);
    float4 w1 = make_float4(acc[r][4], acc[r][5], acc[r][6], acc[r][7]);
    *(float4*)&partials[base + (size_t)(R + r) * D + C] = w0;
    *(float4*)&partials[base + (size_t)(R + r) * D + C + 4] = w1;
  }
}

// ---------------- reduce partials -> 32 class covs + total cov ----------------
__global__ void reduce_k(const float* __restrict__ partials, float* __restrict__ covs) {
  int e = blockIdx.x * blockDim.x + threadIdx.x;  // 0..D*D-1
  double tot = 0.0;
  for (int j = 0; j < NCLS; ++j) {
    double s = 0.0;
    for (int t = 0; t < TSLOT; ++t)
      s += (double)partials[(size_t)(j * TSLOT + t) * (D * D) + e];
    covs[(size_t)j * (D * D) + e] = (float)s;
    tot += s;
  }
  covs[(size_t)NCLS * (D * D) + e] = (float)tot;
}

// ---------------- register-resident Cholesky logdet (one matrix per block) ----
__global__ __launch_bounds__(256) void chol_k(const float* __restrict__ covs,
                                              const int* __restrict__ hist,
                                              int Mtot, double* __restrict__ results) {
  __shared__ float raw[D];
  __shared__ float colL[D];
  __shared__ double red[256];
  const int j = blockIdx.x;
  const float* A = covs + (size_t)j * (D * D);
  const int tid = threadIdx.x;
  const int tr = tid >> 4, tc = tid & 15;
  const int R = tr * 8, C = tc * 8;

  float a[8][8];
#pragma unroll
  for (int r = 0; r < 8; ++r) {
    float4 v0 = *(const float4*)&A[(size_t)(R + r) * D + C];
    float4 v1 = *(const float4*)&A[(size_t)(R + r) * D + C + 4];
    a[r][0] = v0.x; a[r][1] = v0.y; a[r][2] = v0.z; a[r][3] = v0.w;
    a[r][4] = v1.x; a[r][5] = v1.y; a[r][6] = v1.z; a[r][7] = v1.w;
  }

  double ld = 0.0;
  for (int k = 0; k < D; ++k) {
    if (tc == (k >> 3)) {
      const int kc = k & 7;
#pragma unroll
      for (int q = 0; q < 8; ++q)
        if (q == kc) {
#pragma unroll
          for (int r = 0; r < 8; ++r) raw[R + r] = a[r][q];
        }
    }
    __syncthreads();
    if (tid < D) {
      float piv = raw[k];
      if (tid == k) ld += log((double)piv);
      float inv = 1.0f / sqrtf(fmaxf(piv, 1e-30f));
      colL[tid] = (tid > k) ? raw[tid] * inv : 0.f;
    }
    __syncthreads();
    float4 cr0 = *(const float4*)&colL[R];
    float4 cr1 = *(const float4*)&colL[R + 4];
    float4 cc0 = *(const float4*)&colL[C];
    float4 cc1 = *(const float4*)&colL[C + 4];
    float xr[8] = {cr0.x, cr0.y, cr0.z, cr0.w, cr1.x, cr1.y, cr1.z, cr1.w};
    float yc[8] = {cc0.x, cc0.y, cc0.z, cc0.w, cc1.x, cc1.y, cc1.z, cc1.w};
#pragma unroll
    for (int r = 0; r < 8; ++r)
#pragma unroll
      for (int c = 0; c < 8; ++c) a[r][c] = fmaf(-xr[r], yc[c], a[r][c]);
  }

  red[tid] = ld;
  __syncthreads();
  for (int off = 128; off > 0; off >>= 1) {
    if (tid < off) red[tid] += red[tid + off];
    __syncthreads();
  }
  if (tid == 0) {
    double lsum = red[0];
    if (j < NCLS) {
      int mj = hist[j];
      double res = 0.0;
      if (mj > 0) {
        double cj = (double)D / ((double)mj * 0.01);
        res = ((double)D * log(cj) + lsum) * (double)mj / (2.0 * (double)Mtot);
      }
      results[j] = res;
    } else {
      double c = (double)D / ((double)Mtot * 0.01);
      results[NCLS] = ((double)D * log(c) + lsum) * 0.5;
    }
  }
}

// ---------------- combine ----------------
__global__ void final_k(const double* __restrict__ results, float* __restrict__ out) {
  if (threadIdx.x == 0 && blockIdx.x == 0) {
    double s = 0.0;
    for (int j = 0; j < NCLS; ++j) s += results[j];
    out[0] = (float)(s - results[NCLS]);
  }
}

extern "C" void kernel_launch(void* const* d_in, const int* in_sizes, int n_in,
                              void* d_out, int out_size, void* d_ws, size_t ws_size,
                              hipStream_t stream) {
  const float* Z = (const float*)d_in[0];
  const int* label = (const int*)d_in[1];
  const int Mtot = in_sizes[1];
  float* out = (float*)d_out;
  const int NB = (Mtot + CHUNK - 1) / CHUNK;

  // ws layout (bytes):
  //   0    : int hist[32]
  //   256  : int cstart[33]
  //   512  : double results[33]
  //   1024 : int idxbuf[M]
  //   then : float partials[NCLS*TSLOT][D*D]   (32 MiB)  -- blkhist_t/base_t aliased here
  //   then : float covs[NCLS+1][D*D]           (~2.1 MiB)
  char* ws = (char*)d_ws;
  int* hist = (int*)(ws + 0);
  int* cstart = (int*)(ws + 256);
  double* results = (double*)(ws + 512);
  int* idxbuf = (int*)(ws + 1024);
  float* partials = (float*)(ws + 1024 + (size_t)Mtot * sizeof(int));
  float* covs = partials + (size_t)NCLS * TSLOT * D * D;
  // sort scratch aliased over partials (dead once cov_k starts)
  int* blkhist_t = (int*)partials;
  int* base_t = blkhist_t + (size_t)NCLS * NB;

  zero_k<<<1, 64, 0, stream>>>(hist);
  hist_blk_k<<<NB, 64, 0, stream>>>(label, Mtot, NB, blkhist_t, hist);
  prefix_k<<<1, 64, 0, stream>>>(hist, cstart);
  base_k<<<NCLS, 64, 0, stream>>>(blkhist_t, cstart, NB, base_t);
  scatter2_k<<<NB, 64, 0, stream>>>(label, Mtot, NB, base_t, idxbuf);
  cov_k<<<NCLS * TSLOT, 256, 0, stream>>>(Z, idxbuf, hist, cstart, partials);
  reduce_k<<<(D * D) / 256, 256, 0, stream>>>(partials, covs);
  chol_k<<<NCLS + 1, 256, 0, stream>>>(covs, hist, Mtot, results);
  final_k<<<1, 64, 0, stream>>>(results, out);
}

// Round 3
// 186.428 us; speedup vs baseline: 3.9568x; 1.4777x over previous
//
#include <hip/hip_runtime.h>
#include <math.h>

#define D 128
#define NCLS 32
#define TSLOT 16
#define CHUNK 256  // labels per sort block

typedef float f32x16 __attribute__((ext_vector_type(16)));
typedef short bf16x8 __attribute__((ext_vector_type(8)));

// ---------------- zero counters ----------------
__global__ void zero_k(int* hist) {
  int t = threadIdx.x;
  if (t < NCLS) hist[t] = 0;
}

// ---------------- per-block label histogram (+ global hist) ----------------
__global__ __launch_bounds__(64) void hist_blk_k(const int* __restrict__ label, int M,
                                                 int NB, int* __restrict__ blkhist_t,
                                                 int* __restrict__ hist) {
  __shared__ int h[NCLS];
  const int lane = threadIdx.x;
  const int b = blockIdx.x;
  if (lane < NCLS) h[lane] = 0;
  __syncthreads();
  const int s0 = b * CHUNK;
#pragma unroll
  for (int it = 0; it < CHUNK / 64; ++it) {
    int i = s0 + it * 64 + lane;
    if (i < M) atomicAdd(&h[label[i]], 1);
  }
  __syncthreads();
  if (lane < NCLS) {
    blkhist_t[lane * NB + b] = h[lane];
    atomicAdd(&hist[lane], h[lane]);
  }
}

// ---------------- exclusive prefix over classes ----------------
__global__ void prefix_k(const int* __restrict__ hist, int* __restrict__ cstart) {
  if (threadIdx.x == 0) {
    int run = 0;
    for (int j = 0; j < NCLS; ++j) { cstart[j] = run; run += hist[j]; }
    cstart[NCLS] = run;
  }
}

// ---------------- per-class scan over blocks: base_t[j][b] ----------------
__global__ __launch_bounds__(64) void base_k(const int* __restrict__ blkhist_t,
                                             const int* __restrict__ cstart, int NB,
                                             int* __restrict__ base_t) {
  const int j = blockIdx.x;
  const int lane = threadIdx.x;
  const int K = (NB + 63) / 64;
  int vals[32];
  int run = 0;
  for (int k = 0; k < K; ++k) {
    int b = lane * K + k;
    int v = (b < NB) ? blkhist_t[j * NB + b] : 0;
    vals[k] = v;
    run += v;
  }
  int incl = run;
  for (int off = 1; off < 64; off <<= 1) {
    int o = __shfl_up(incl, off);
    if (lane >= off) incl += o;
  }
  int pos = cstart[j] + (incl - run);
  for (int k = 0; k < K; ++k) {
    int b = lane * K + k;
    if (b < NB) base_t[j * NB + b] = pos;
    pos += vals[k];
  }
}

// ---------------- stable, atomic-free scatter (1 wave / block) ----------------
__global__ __launch_bounds__(64) void scatter2_k(const int* __restrict__ label, int M,
                                                 int NB, const int* __restrict__ base_t,
                                                 int* __restrict__ idxbuf) {
  __shared__ int cur[NCLS];
  const int b = blockIdx.x;
  const int lane = threadIdx.x;
  if (lane < NCLS) cur[lane] = base_t[lane * NB + b];
  __syncthreads();
  const int s0 = b * CHUNK;
#pragma unroll
  for (int it = 0; it < CHUNK / 64; ++it) {
    int i = s0 + it * 64 + lane;
    int j = (i < M) ? label[i] : -1;
    unsigned long long mask = 0;
#pragma unroll
    for (int q = 0; q < NCLS; ++q) {
      unsigned long long mm = __ballot(j == q);
      if (j == q) mask = mm;
    }
    if (j >= 0) {
      int myoff = __popcll(mask & ((1ull << lane) - 1ull));
      int basec = cur[j];
      idxbuf[basec + myoff] = i;
      if (myoff == 0) cur[j] = basec + __popcll(mask);
    }
    __syncthreads();
  }
}

// ---------------- fp32 -> (hi, lo) bf16 split, RNE ----------------
__device__ inline void bsplit(float x, short& hi, short& lo) {
  unsigned u = __float_as_uint(x);
  unsigned rh = u + 0x7fffu + ((u >> 16) & 1u);
  unsigned short h = (unsigned short)(rh >> 16);
  float hf = __uint_as_float((unsigned)h << 16);
  float l = x - hf;  // exact
  unsigned ul = __float_as_uint(l);
  unsigned rl = ul + 0x7fffu + ((ul >> 16) & 1u);
  hi = (short)h;
  lo = (short)(rl >> 16);
}

// ---------------- per-class Gram via bf16-split MFMA ----------------
// grid = NCLS*TSLOT, 512 threads (8 waves). Waves 0..3: G1 = Hi.Hi^T tile-strip
// r=w; waves 4..7: G2 = Hi.Lo^T strip r=w-4. 64-row chunks staged transposed
// into LDS as T[col][row] (bf16, XOR-swizzled). partial = G1 + G2 + G2^T.
__global__ __launch_bounds__(512, 4) void cov_k(const float* __restrict__ Z,
                                                const int* __restrict__ idxbuf,
                                                const int* __restrict__ hist,
                                                const int* __restrict__ cstart,
                                                float* __restrict__ partials) {
  // arena: staging Thi [128 cols][64 rows] bf16 = 16 KB at 0, Tlo at 16384;
  // epilogue overlays float g2buf[128][129] = 66048 B.
  __shared__ __attribute__((aligned(16))) char arena[66048];

  const int b = blockIdx.x;
  const int cls = b / TSLOT, slot = b % TSLOT;
  const int t = threadIdx.x;
  const int lane = t & 63;
  const int w = t >> 6;
  const int r = w & 3;        // tile-strip (32 output rows)
  const int pass = w >> 2;    // 0: G1 (B=Hi), 1: G2 (B=Lo)
  const int col4 = t & 31;    // staging: float4 col group
  const int rg = t >> 5;      // staging: row group (4 rows)

  const int mj = hist[cls];
  const int seg0 = cstart[cls];
  const int segend = seg0 + mj;
  const int nch = (mj + 63) / 64;

  f32x16 acc[4];
#pragma unroll
  for (int c = 0; c < 4; ++c)
#pragma unroll
    for (int i = 0; i < 16; ++i) acc[c][i] = 0.f;

  const int pcol = r * 32 + (lane & 31);
  const int h = lane >> 5;
  const int aswz = (pcol & 7) << 4;
  char* const bbase = arena + (pass ? 16384 : 0);

  float4 pv[4];
  {
    const int ch = slot;
    const int r0 = seg0 + ch * 64;
#pragma unroll
    for (int i = 0; i < 4; ++i) {
      int gr = r0 + rg * 4 + i;
      if (ch < nch && gr < segend) {
        int ridx = idxbuf[gr];
        pv[i] = *(const float4*)(Z + (size_t)ridx * D + col4 * 4);
      } else {
        pv[i] = make_float4(0.f, 0.f, 0.f, 0.f);
      }
    }
  }

  for (int ch = slot; ch < nch; ch += TSLOT) {
    __syncthreads();  // prior MFMA reads of arena done
    // convert + 4x4 transpose + swizzled ds_write
    {
      float xs[4][4];
      xs[0][0] = pv[0].x; xs[0][1] = pv[0].y; xs[0][2] = pv[0].z; xs[0][3] = pv[0].w;
      xs[1][0] = pv[1].x; xs[1][1] = pv[1].y; xs[1][2] = pv[1].z; xs[1][3] = pv[1].w;
      xs[2][0] = pv[2].x; xs[2][1] = pv[2].y; xs[2][2] = pv[2].z; xs[2][3] = pv[2].w;
      xs[3][0] = pv[3].x; xs[3][1] = pv[3].y; xs[3][2] = pv[3].z; xs[3][3] = pv[3].w;
#pragma unroll
      for (int j = 0; j < 4; ++j) {
        short h0, h1, h2, h3, l0, l1, l2, l3;
        bsplit(xs[0][j], h0, l0);
        bsplit(xs[1][j], h1, l1);
        bsplit(xs[2][j], h2, l2);
        bsplit(xs[3][j], h3, l3);
        const int cc = col4 * 4 + j;
        const int off = cc * 128 + ((rg * 8) ^ ((cc & 7) << 4));
        *(short4*)(arena + off) = make_short4(h0, h1, h2, h3);
        *(short4*)(arena + 16384 + off) = make_short4(l0, l1, l2, l3);
      }
    }
    __syncthreads();
    // prefetch next chunk (T14: loads in flight under MFMA phase)
    {
      const int chn = ch + TSLOT;
      const int r0 = seg0 + chn * 64;
#pragma unroll
      for (int i = 0; i < 4; ++i) {
        int gr = r0 + rg * 4 + i;
        if (chn < nch && gr < segend) {
          int ridx = idxbuf[gr];
          pv[i] = *(const float4*)(Z + (size_t)ridx * D + col4 * 4);
        } else {
          pv[i] = make_float4(0.f, 0.f, 0.f, 0.f);
        }
      }
    }
    // MFMA over 4 k-steps of 16 staged rows
#pragma unroll
    for (int kk = 0; kk < 4; ++kk) {
      const int koff = kk * 32 + h * 16;
      bf16x8 a = *(const bf16x8*)(arena + pcol * 128 + (koff ^ aswz));
#pragma unroll
      for (int c = 0; c < 4; ++c) {
        const int qcol = c * 32 + (lane & 31);
        bf16x8 bb = *(const bf16x8*)(bbase + qcol * 128 + (koff ^ ((qcol & 7) << 4)));
        acc[c] = __builtin_amdgcn_mfma_f32_32x32x16_bf16(a, bb, acc[c], 0, 0, 0);
      }
    }
  }

  // epilogue: partial = G1 + G2 + G2^T via LDS symmetrization
  __syncthreads();
  float* g2 = (float*)arena;
  if (pass == 1) {
#pragma unroll
    for (int c = 0; c < 4; ++c)
#pragma unroll
      for (int i = 0; i < 16; ++i) {
        int prow = r * 32 + (i & 3) + 8 * (i >> 2) + 4 * h;
        int qcol = c * 32 + (lane & 31);
        g2[prow * 129 + qcol] = acc[c][i];
      }
  }
  __syncthreads();
  if (pass == 0) {
    size_t base = (size_t)b * (D * D);
#pragma unroll
    for (int c = 0; c < 4; ++c)
#pragma unroll
      for (int i = 0; i < 16; ++i) {
        int prow = r * 32 + (i & 3) + 8 * (i >> 2) + 4 * h;
        int qcol = c * 32 + (lane & 31);
        float v = acc[c][i] + g2[prow * 129 + qcol] + g2[qcol * 129 + prow];
        partials[base + (size_t)prow * D + qcol] = v;
      }
  }
}

// ---------------- reduce partials -> 32 class covs + total cov ----------------
__global__ void reduce_k(const float* __restrict__ partials, float* __restrict__ covs) {
  int e = blockIdx.x * blockDim.x + threadIdx.x;
  double tot = 0.0;
  for (int j = 0; j < NCLS; ++j) {
    double s = 0.0;
    for (int t = 0; t < TSLOT; ++t)
      s += (double)partials[(size_t)(j * TSLOT + t) * (D * D) + e];
    covs[(size_t)j * (D * D) + e] = (float)s;
    tot += s;
  }
  covs[(size_t)NCLS * (D * D) + e] = (float)tot;
}

// ---------------- register-resident Cholesky logdet (one matrix per block) ----
__global__ __launch_bounds__(256) void chol_k(const float* __restrict__ covs,
                                              const int* __restrict__ hist,
                                              int Mtot, double* __restrict__ results) {
  __shared__ float raw[D];
  __shared__ float colL[D];
  __shared__ double red[256];
  const int j = blockIdx.x;
  const float* A = covs + (size_t)j * (D * D);
  const int tid = threadIdx.x;
  const int tr = tid >> 4, tc = tid & 15;
  const int R = tr * 8, C = tc * 8;

  float a[8][8];
#pragma unroll
  for (int r = 0; r < 8; ++r) {
    float4 v0 = *(const float4*)&A[(size_t)(R + r) * D + C];
    float4 v1 = *(const float4*)&A[(size_t)(R + r) * D + C + 4];
    a[r][0] = v0.x; a[r][1] = v0.y; a[r][2] = v0.z; a[r][3] = v0.w;
    a[r][4] = v1.x; a[r][5] = v1.y; a[r][6] = v1.z; a[r][7] = v1.w;
  }

  double ld = 0.0;
  for (int k = 0; k < D; ++k) {
    if (tc == (k >> 3)) {
      const int kc = k & 7;
#pragma unroll
      for (int q = 0; q < 8; ++q)
        if (q == kc) {
#pragma unroll
          for (int r = 0; r < 8; ++r) raw[R + r] = a[r][q];
        }
    }
    __syncthreads();
    if (tid < D) {
      float piv = raw[k];
      if (tid == k) ld += log((double)piv);
      float inv = 1.0f / sqrtf(fmaxf(piv, 1e-30f));
      colL[tid] = (tid > k) ? raw[tid] * inv : 0.f;
    }
    __syncthreads();
    float4 cr0 = *(const float4*)&colL[R];
    float4 cr1 = *(const float4*)&colL[R + 4];
    float4 cc0 = *(const float4*)&colL[C];
    float4 cc1 = *(const float4*)&colL[C + 4];
    float xr[8] = {cr0.x, cr0.y, cr0.z, cr0.w, cr1.x, cr1.y, cr1.z, cr1.w};
    float yc[8] = {cc0.x, cc0.y, cc0.z, cc0.w, cc1.x, cc1.y, cc1.z, cc1.w};
#pragma unroll
    for (int r = 0; r < 8; ++r)
#pragma unroll
      for (int c = 0; c < 8; ++c) a[r][c] = fmaf(-xr[r], yc[c], a[r][c]);
  }

  red[tid] = ld;
  __syncthreads();
  for (int off = 128; off > 0; off >>= 1) {
    if (tid < off) red[tid] += red[tid + off];
    __syncthreads();
  }
  if (tid == 0) {
    double lsum = red[0];
    if (j < NCLS) {
      int mj = hist[j];
      double res = 0.0;
      if (mj > 0) {
        double cj = (double)D / ((double)mj * 0.01);
        res = ((double)D * log(cj) + lsum) * (double)mj / (2.0 * (double)Mtot);
      }
      results[j] = res;
    } else {
      double c = (double)D / ((double)Mtot * 0.01);
      results[NCLS] = ((double)D * log(c) + lsum) * 0.5;
    }
  }
}

// ---------------- combine ----------------
__global__ void final_k(const double* __restrict__ results, float* __restrict__ out) {
  if (threadIdx.x == 0 && blockIdx.x == 0) {
    double s = 0.0;
    for (int j = 0; j < NCLS; ++j) s += results[j];
    out[0] = (float)(s - results[NCLS]);
  }
}

extern "C" void kernel_launch(void* const* d_in, const int* in_sizes, int n_in,
                              void* d_out, int out_size, void* d_ws, size_t ws_size,
                              hipStream_t stream) {
  const float* Z = (const float*)d_in[0];
  const int* label = (const int*)d_in[1];
  const int Mtot = in_sizes[1];
  float* out = (float*)d_out;
  const int NB = (Mtot + CHUNK - 1) / CHUNK;

  char* ws = (char*)d_ws;
  int* hist = (int*)(ws + 0);
  int* cstart = (int*)(ws + 256);
  double* results = (double*)(ws + 512);
  int* idxbuf = (int*)(ws + 1024);
  float* partials = (float*)(ws + 1024 + (size_t)Mtot * sizeof(int));
  float* covs = partials + (size_t)NCLS * TSLOT * D * D;
  int* blkhist_t = (int*)partials;  // aliased, dead before cov_k
  int* base_t = blkhist_t + (size_t)NCLS * NB;

  zero_k<<<1, 64, 0, stream>>>(hist);
  hist_blk_k<<<NB, 64, 0, stream>>>(label, Mtot, NB, blkhist_t, hist);
  prefix_k<<<1, 64, 0, stream>>>(hist, cstart);
  base_k<<<NCLS, 64, 0, stream>>>(blkhist_t, cstart, NB, base_t);
  scatter2_k<<<NB, 64, 0, stream>>>(label, Mtot, NB, base_t, idxbuf);
  cov_k<<<NCLS * TSLOT, 512, 0, stream>>>(Z, idxbuf, hist, cstart, partials);
  reduce_k<<<(D * D) / 256, 256, 0, stream>>>(partials, covs);
  chol_k<<<NCLS + 1, 256, 0, stream>>>(covs, hist, Mtot, results);
  final_k<<<1, 64, 0, stream>>>(results, out);
}

// Round 4
// 139.130 us; speedup vs baseline: 5.3019x; 1.3400x over previous
//
#include <hip/hip_runtime.h>
#include <math.h>

#define D 128
#define NCLS 32
#define TSLOT 16
#define CHUNK 256  // labels per sort block

typedef float f32x16 __attribute__((ext_vector_type(16)));
typedef short bf16x8 __attribute__((ext_vector_type(8)));

// ---------------- zero counters ----------------
__global__ void zero_k(int* hist) {
  int t = threadIdx.x;
  if (t < NCLS) hist[t] = 0;
}

// ---------------- per-block label histogram (+ global hist) ----------------
__global__ __launch_bounds__(64) void hist_blk_k(const int* __restrict__ label, int M,
                                                 int NB, int* __restrict__ blkhist_t,
                                                 int* __restrict__ hist) {
  __shared__ int h[NCLS];
  const int lane = threadIdx.x;
  const int b = blockIdx.x;
  if (lane < NCLS) h[lane] = 0;
  __syncthreads();
  const int s0 = b * CHUNK;
#pragma unroll
  for (int it = 0; it < CHUNK / 64; ++it) {
    int i = s0 + it * 64 + lane;
    if (i < M) atomicAdd(&h[label[i]], 1);
  }
  __syncthreads();
  if (lane < NCLS) {
    blkhist_t[lane * NB + b] = h[lane];
    atomicAdd(&hist[lane], h[lane]);
  }
}

// ---------------- exclusive prefix over classes ----------------
__global__ void prefix_k(const int* __restrict__ hist, int* __restrict__ cstart) {
  if (threadIdx.x == 0) {
    int run = 0;
    for (int j = 0; j < NCLS; ++j) { cstart[j] = run; run += hist[j]; }
    cstart[NCLS] = run;
  }
}

// ---------------- per-class scan over blocks: base_t[j][b] ----------------
__global__ __launch_bounds__(64) void base_k(const int* __restrict__ blkhist_t,
                                             const int* __restrict__ cstart, int NB,
                                             int* __restrict__ base_t) {
  const int j = blockIdx.x;
  const int lane = threadIdx.x;
  const int K = (NB + 63) / 64;
  int vals[32];
  int run = 0;
  for (int k = 0; k < K; ++k) {
    int b = lane * K + k;
    int v = (b < NB) ? blkhist_t[j * NB + b] : 0;
    vals[k] = v;
    run += v;
  }
  int incl = run;
  for (int off = 1; off < 64; off <<= 1) {
    int o = __shfl_up(incl, off);
    if (lane >= off) incl += o;
  }
  int pos = cstart[j] + (incl - run);
  for (int k = 0; k < K; ++k) {
    int b = lane * K + k;
    if (b < NB) base_t[j * NB + b] = pos;
    pos += vals[k];
  }
}

// ---------------- stable, atomic-free scatter (1 wave / block) ----------------
__global__ __launch_bounds__(64) void scatter2_k(const int* __restrict__ label, int M,
                                                 int NB, const int* __restrict__ base_t,
                                                 int* __restrict__ idxbuf) {
  __shared__ int cur[NCLS];
  const int b = blockIdx.x;
  const int lane = threadIdx.x;
  if (lane < NCLS) cur[lane] = base_t[lane * NB + b];
  __syncthreads();
  const int s0 = b * CHUNK;
#pragma unroll
  for (int it = 0; it < CHUNK / 64; ++it) {
    int i = s0 + it * 64 + lane;
    int j = (i < M) ? label[i] : -1;
    unsigned long long mask = 0;
#pragma unroll
    for (int q = 0; q < NCLS; ++q) {
      unsigned long long mm = __ballot(j == q);
      if (j == q) mask = mm;
    }
    if (j >= 0) {
      int myoff = __popcll(mask & ((1ull << lane) - 1ull));
      int basec = cur[j];
      idxbuf[basec + myoff] = i;
      if (myoff == 0) cur[j] = basec + __popcll(mask);
    }
    __syncthreads();
  }
}

// ---------------- fp32 -> (hi, lo) bf16 split, RNE ----------------
__device__ inline void bsplit(float x, short& hi, short& lo) {
  unsigned u = __float_as_uint(x);
  unsigned rh = u + 0x7fffu + ((u >> 16) & 1u);
  unsigned short h = (unsigned short)(rh >> 16);
  float hf = __uint_as_float((unsigned)h << 16);
  float l = x - hf;  // exact
  unsigned ul = __float_as_uint(l);
  unsigned rl = ul + 0x7fffu + ((ul >> 16) & 1u);
  hi = (short)h;
  lo = (short)(rl >> 16);
}

// ---------------- per-class Gram via bf16-split MFMA ----------------
__global__ __launch_bounds__(512, 4) void cov_k(const float* __restrict__ Z,
                                                const int* __restrict__ idxbuf,
                                                const int* __restrict__ hist,
                                                const int* __restrict__ cstart,
                                                float* __restrict__ partials) {
  __shared__ __attribute__((aligned(16))) char arena[66048];

  const int b = blockIdx.x;
  const int cls = b / TSLOT, slot = b % TSLOT;
  const int t = threadIdx.x;
  const int lane = t & 63;
  const int w = t >> 6;
  const int r = w & 3;
  const int pass = w >> 2;
  const int col4 = t & 31;
  const int rg = t >> 5;

  const int mj = hist[cls];
  const int seg0 = cstart[cls];
  const int segend = seg0 + mj;
  const int nch = (mj + 63) / 64;

  f32x16 acc[4];
#pragma unroll
  for (int c = 0; c < 4; ++c)
#pragma unroll
    for (int i = 0; i < 16; ++i) acc[c][i] = 0.f;

  const int pcol = r * 32 + (lane & 31);
  const int h = lane >> 5;
  const int aswz = (pcol & 7) << 4;
  char* const bbase = arena + (pass ? 16384 : 0);

  float4 pv[4];
  {
    const int ch = slot;
    const int r0 = seg0 + ch * 64;
#pragma unroll
    for (int i = 0; i < 4; ++i) {
      int gr = r0 + rg * 4 + i;
      if (ch < nch && gr < segend) {
        int ridx = idxbuf[gr];
        pv[i] = *(const float4*)(Z + (size_t)ridx * D + col4 * 4);
      } else {
        pv[i] = make_float4(0.f, 0.f, 0.f, 0.f);
      }
    }
  }

  for (int ch = slot; ch < nch; ch += TSLOT) {
    __syncthreads();
    {
      float xs[4][4];
      xs[0][0] = pv[0].x; xs[0][1] = pv[0].y; xs[0][2] = pv[0].z; xs[0][3] = pv[0].w;
      xs[1][0] = pv[1].x; xs[1][1] = pv[1].y; xs[1][2] = pv[1].z; xs[1][3] = pv[1].w;
      xs[2][0] = pv[2].x; xs[2][1] = pv[2].y; xs[2][2] = pv[2].z; xs[2][3] = pv[2].w;
      xs[3][0] = pv[3].x; xs[3][1] = pv[3].y; xs[3][2] = pv[3].z; xs[3][3] = pv[3].w;
#pragma unroll
      for (int j = 0; j < 4; ++j) {
        short h0, h1, h2, h3, l0, l1, l2, l3;
        bsplit(xs[0][j], h0, l0);
        bsplit(xs[1][j], h1, l1);
        bsplit(xs[2][j], h2, l2);
        bsplit(xs[3][j], h3, l3);
        const int cc = col4 * 4 + j;
        const int off = cc * 128 + ((rg * 8) ^ ((cc & 7) << 4));
        *(short4*)(arena + off) = make_short4(h0, h1, h2, h3);
        *(short4*)(arena + 16384 + off) = make_short4(l0, l1, l2, l3);
      }
    }
    __syncthreads();
    {
      const int chn = ch + TSLOT;
      const int r0 = seg0 + chn * 64;
#pragma unroll
      for (int i = 0; i < 4; ++i) {
        int gr = r0 + rg * 4 + i;
        if (chn < nch && gr < segend) {
          int ridx = idxbuf[gr];
          pv[i] = *(const float4*)(Z + (size_t)ridx * D + col4 * 4);
        } else {
          pv[i] = make_float4(0.f, 0.f, 0.f, 0.f);
        }
      }
    }
#pragma unroll
    for (int kk = 0; kk < 4; ++kk) {
      const int koff = kk * 32 + h * 16;
      bf16x8 a = *(const bf16x8*)(arena + pcol * 128 + (koff ^ aswz));
#pragma unroll
      for (int c = 0; c < 4; ++c) {
        const int qcol = c * 32 + (lane & 31);
        bf16x8 bb = *(const bf16x8*)(bbase + qcol * 128 + (koff ^ ((qcol & 7) << 4)));
        acc[c] = __builtin_amdgcn_mfma_f32_32x32x16_bf16(a, bb, acc[c], 0, 0, 0);
      }
    }
  }

  __syncthreads();
  float* g2 = (float*)arena;
  if (pass == 1) {
#pragma unroll
    for (int c = 0; c < 4; ++c)
#pragma unroll
      for (int i = 0; i < 16; ++i) {
        int prow = r * 32 + (i & 3) + 8 * (i >> 2) + 4 * h;
        int qcol = c * 32 + (lane & 31);
        g2[prow * 129 + qcol] = acc[c][i];
      }
  }
  __syncthreads();
  if (pass == 0) {
    size_t base = (size_t)b * (D * D);
#pragma unroll
    for (int c = 0; c < 4; ++c)
#pragma unroll
      for (int i = 0; i < 16; ++i) {
        int prow = r * 32 + (i & 3) + 8 * (i >> 2) + 4 * h;
        int qcol = c * 32 + (lane & 31);
        float v = acc[c][i] + g2[prow * 129 + qcol] + g2[qcol * 129 + prow];
        partials[base + (size_t)prow * D + qcol] = v;
      }
  }
}

// ---------------- reduce partials -> 32 class covs + total cov ----------------
__global__ void reduce_k(const float* __restrict__ partials, float* __restrict__ covs) {
  int e = blockIdx.x * blockDim.x + threadIdx.x;
  double tot = 0.0;
  for (int j = 0; j < NCLS; ++j) {
    double s = 0.0;
    for (int t = 0; t < TSLOT; ++t)
      s += (double)partials[(size_t)(j * TSLOT + t) * (D * D) + e];
    covs[(size_t)j * (D * D) + e] = (float)s;
    tot += s;
  }
  covs[(size_t)NCLS * (D * D) + e] = (float)tot;
}

// ---------------- blocked Cholesky logdet ----------------
// One block (256 thr) per matrix. Panel width 32, 4 panels:
//   diag: wave 0, row-per-lane, shfl-only 32-step factor (no barriers)
//   solve: thread-per-row forward substitution vs LDS L11
//   trailing: A22 -= L21*L21^T, T x T register tiles (T = N2/16)
template <int T>
__device__ void trailing_upd(float (*As)[132], int pbase, int tid) {
  const int ty = tid >> 4, tx = tid & 15;
  const int r0 = pbase + 32 + ty * T;
  const int c0 = pbase + 32 + tx * T;
  float acc[T][T];
#pragma unroll
  for (int a = 0; a < T; ++a)
#pragma unroll
    for (int b = 0; b < T; ++b) acc[a][b] = 0.f;
#pragma unroll
  for (int j0 = 0; j0 < 32; j0 += 8) {
    float ar[T][8], ac[T][8];
#pragma unroll
    for (int a = 0; a < T; ++a) {
      float4 v0 = *(const float4*)&As[r0 + a][pbase + j0];
      float4 v1 = *(const float4*)&As[r0 + a][pbase + j0 + 4];
      ar[a][0] = v0.x; ar[a][1] = v0.y; ar[a][2] = v0.z; ar[a][3] = v0.w;
      ar[a][4] = v1.x; ar[a][5] = v1.y; ar[a][6] = v1.z; ar[a][7] = v1.w;
    }
#pragma unroll
    for (int b = 0; b < T; ++b) {
      float4 v0 = *(const float4*)&As[c0 + b][pbase + j0];
      float4 v1 = *(const float4*)&As[c0 + b][pbase + j0 + 4];
      ac[b][0] = v0.x; ac[b][1] = v0.y; ac[b][2] = v0.z; ac[b][3] = v0.w;
      ac[b][4] = v1.x; ac[b][5] = v1.y; ac[b][6] = v1.z; ac[b][7] = v1.w;
    }
#pragma unroll
    for (int jj = 0; jj < 8; ++jj)
#pragma unroll
      for (int a = 0; a < T; ++a)
#pragma unroll
        for (int b = 0; b < T; ++b)
          acc[a][b] = fmaf(ar[a][jj], ac[b][jj], acc[a][b]);
  }
#pragma unroll
  for (int a = 0; a < T; ++a)
#pragma unroll
    for (int b = 0; b < T; ++b)
      As[r0 + a][c0 + b] -= acc[a][b];
}

__global__ __launch_bounds__(256) void chol_k(const float* __restrict__ covs,
                                              const int* __restrict__ hist,
                                              int Mtot, double* __restrict__ results) {
  __shared__ float As[128][132];
  __shared__ float Pl[32][36];
  __shared__ float invd[32];
  __shared__ double red[64];
  const int j = blockIdx.x;
  const float* A = covs + (size_t)j * (D * D);
  const int tid = threadIdx.x;
  const int lane = tid & 63;
  const int w = tid >> 6;

#pragma unroll
  for (int it = 0; it < 16; ++it) {
    int e = it * 1024 + tid * 4;
    int r = e >> 7, c = e & 127;
    *(float4*)&As[r][c] = *(const float4*)&A[e];
  }
  __syncthreads();

  double lda = 0.0;
  for (int p = 0; p < 4; ++p) {
    const int pbase = p * 32;
    // ---- diag factor (wave 0; lanes 32..63 mirror, contribute log(1)=0)
    if (w == 0) {
      const int l = lane & 31;
      float row[32];
#pragma unroll
      for (int c4 = 0; c4 < 8; ++c4) {
        float4 v = *(const float4*)&As[pbase + l][pbase + c4 * 4];
        row[c4 * 4 + 0] = v.x; row[c4 * 4 + 1] = v.y;
        row[c4 * 4 + 2] = v.z; row[c4 * 4 + 3] = v.w;
      }
      float mypiv = 1.f, myinv = 0.f;
#pragma unroll
      for (int k = 0; k < 32; ++k) {
        float piv = __shfl(row[k], k);
        float inv = rsqrtf(piv);
        inv = inv * (1.5f - 0.5f * piv * inv * inv);  // NR -> ~1ulp
        if (lane == k) { mypiv = piv; myinv = inv; }
        row[k] *= inv;  // row[k] := L[lane][k]
        float lrk = row[k];
#pragma unroll
        for (int c = k + 1; c < 32; ++c) {
          float lck = __shfl(row[k], c);  // = L[c][k]
          row[c] = fmaf(-lrk, lck, row[c]);
        }
      }
      if (lane < 32) {
#pragma unroll
        for (int c4 = 0; c4 < 8; ++c4)
          *(float4*)&Pl[lane][c4 * 4] =
              make_float4(row[c4 * 4], row[c4 * 4 + 1], row[c4 * 4 + 2], row[c4 * 4 + 3]);
        invd[lane] = myinv;
      }
      lda += log((double)mypiv);
    }
    __syncthreads();
    // ---- L21 solve: thread tid handles trailing row pbase+32+tid
    const int N2 = 96 - pbase;
    if (tid < N2) {
      const int R = pbase + 32 + tid;
      float x[32];
#pragma unroll
      for (int c4 = 0; c4 < 8; ++c4) {
        float4 v = *(const float4*)&As[R][pbase + c4 * 4];
        x[c4 * 4 + 0] = v.x; x[c4 * 4 + 1] = v.y;
        x[c4 * 4 + 2] = v.z; x[c4 * 4 + 3] = v.w;
      }
#pragma unroll
      for (int jj = 0; jj < 32; ++jj) {
        float s = x[jj];
        const float* pj = &Pl[jj][0];
        int i = 0;
#pragma unroll
        for (; i + 4 <= jj; i += 4) {
          float4 pv = *(const float4*)&pj[i];
          s = fmaf(-x[i], pv.x,
              fmaf(-x[i + 1], pv.y, fmaf(-x[i + 2], pv.z, fmaf(-x[i + 3], pv.w, s))));
        }
#pragma unroll
        for (; i < jj; ++i) s = fmaf(-x[i], pj[i], s);
        x[jj] = s * invd[jj];
      }
#pragma unroll
      for (int c4 = 0; c4 < 8; ++c4)
        *(float4*)&As[R][pbase + c4 * 4] =
            make_float4(x[c4 * 4], x[c4 * 4 + 1], x[c4 * 4 + 2], x[c4 * 4 + 3]);
    }
    __syncthreads();
    // ---- trailing update
    if (N2 == 96) trailing_upd<6>(As, pbase, tid);
    else if (N2 == 64) trailing_upd<4>(As, pbase, tid);
    else if (N2 == 32) trailing_upd<2>(As, pbase, tid);
    __syncthreads();
  }

  if (w == 0) red[lane] = lda;
  __syncthreads();
  if (tid == 0) {
    double lsum = 0.0;
    for (int i = 0; i < 64; ++i) lsum += red[i];
    if (j < NCLS) {
      int mj = hist[j];
      double res = 0.0;
      if (mj > 0) {
        double cj = (double)D / ((double)mj * 0.01);
        res = ((double)D * log(cj) + lsum) * (double)mj / (2.0 * (double)Mtot);
      }
      results[j] = res;
    } else {
      double c = (double)D / ((double)Mtot * 0.01);
      results[NCLS] = ((double)D * log(c) + lsum) * 0.5;
    }
  }
}

// ---------------- combine ----------------
__global__ void final_k(const double* __restrict__ results, float* __restrict__ out) {
  if (threadIdx.x == 0 && blockIdx.x == 0) {
    double s = 0.0;
    for (int j = 0; j < NCLS; ++j) s += results[j];
    out[0] = (float)(s - results[NCLS]);
  }
}

extern "C" void kernel_launch(void* const* d_in, const int* in_sizes, int n_in,
                              void* d_out, int out_size, void* d_ws, size_t ws_size,
                              hipStream_t stream) {
  const float* Z = (const float*)d_in[0];
  const int* label = (const int*)d_in[1];
  const int Mtot = in_sizes[1];
  float* out = (float*)d_out;
  const int NB = (Mtot + CHUNK - 1) / CHUNK;

  char* ws = (char*)d_ws;
  int* hist = (int*)(ws + 0);
  int* cstart = (int*)(ws + 256);
  double* results = (double*)(ws + 512);
  int* idxbuf = (int*)(ws + 1024);
  float* partials = (float*)(ws + 1024 + (size_t)Mtot * sizeof(int));
  float* covs = partials + (size_t)NCLS * TSLOT * D * D;
  int* blkhist_t = (int*)partials;  // aliased, dead before cov_k
  int* base_t = blkhist_t + (size_t)NCLS * NB;

  zero_k<<<1, 64, 0, stream>>>(hist);
  hist_blk_k<<<NB, 64, 0, stream>>>(label, Mtot, NB, blkhist_t, hist);
  prefix_k<<<1, 64, 0, stream>>>(hist, cstart);
  base_k<<<NCLS, 64, 0, stream>>>(blkhist_t, cstart, NB, base_t);
  scatter2_k<<<NB, 64, 0, stream>>>(label, Mtot, NB, base_t, idxbuf);
  cov_k<<<NCLS * TSLOT, 512, 0, stream>>>(Z, idxbuf, hist, cstart, partials);
  reduce_k<<<(D * D) / 256, 256, 0, stream>>>(partials, covs);
  chol_k<<<NCLS + 1, 256, 0, stream>>>(covs, hist, Mtot, results);
  final_k<<<1, 64, 0, stream>>>(results, out);
}

// Round 5
// 138.337 us; speedup vs baseline: 5.3324x; 1.0057x over previous
//
#include <hip/hip_runtime.h>
#include <math.h>

#define D 128
#define NCLS 32
#define TSLOT 16
#define CHUNK 256  // labels per sort block

typedef float f32x16 __attribute__((ext_vector_type(16)));
typedef short bf16x8 __attribute__((ext_vector_type(8)));

// ---------------- zero counters ----------------
__global__ void zero_k(int* hist) {
  int t = threadIdx.x;
  if (t < NCLS) hist[t] = 0;
}

// ---------------- per-block label histogram (+ global hist) ----------------
__global__ __launch_bounds__(64) void hist_blk_k(const int* __restrict__ label, int M,
                                                 int NB, int* __restrict__ blkhist_t,
                                                 int* __restrict__ hist) {
  __shared__ int h[NCLS];
  const int lane = threadIdx.x;
  const int b = blockIdx.x;
  if (lane < NCLS) h[lane] = 0;
  __syncthreads();
  const int s0 = b * CHUNK;
#pragma unroll
  for (int it = 0; it < CHUNK / 64; ++it) {
    int i = s0 + it * 64 + lane;
    if (i < M) atomicAdd(&h[label[i]], 1);
  }
  __syncthreads();
  if (lane < NCLS) {
    blkhist_t[lane * NB + b] = h[lane];
    atomicAdd(&hist[lane], h[lane]);
  }
}

// ---------------- exclusive prefix over classes ----------------
__global__ void prefix_k(const int* __restrict__ hist, int* __restrict__ cstart) {
  if (threadIdx.x == 0) {
    int run = 0;
    for (int j = 0; j < NCLS; ++j) { cstart[j] = run; run += hist[j]; }
    cstart[NCLS] = run;
  }
}

// ---------------- per-class scan over blocks: base_t[j][b] ----------------
__global__ __launch_bounds__(64) void base_k(const int* __restrict__ blkhist_t,
                                             const int* __restrict__ cstart, int NB,
                                             int* __restrict__ base_t) {
  const int j = blockIdx.x;
  const int lane = threadIdx.x;
  const int K = (NB + 63) / 64;
  int vals[32];
  int run = 0;
  for (int k = 0; k < K; ++k) {
    int b = lane * K + k;
    int v = (b < NB) ? blkhist_t[j * NB + b] : 0;
    vals[k] = v;
    run += v;
  }
  int incl = run;
  for (int off = 1; off < 64; off <<= 1) {
    int o = __shfl_up(incl, off);
    if (lane >= off) incl += o;
  }
  int pos = cstart[j] + (incl - run);
  for (int k = 0; k < K; ++k) {
    int b = lane * K + k;
    if (b < NB) base_t[j * NB + b] = pos;
    pos += vals[k];
  }
}

// ---------------- stable, atomic-free scatter (1 wave / block) ----------------
__global__ __launch_bounds__(64) void scatter2_k(const int* __restrict__ label, int M,
                                                 int NB, const int* __restrict__ base_t,
                                                 int* __restrict__ idxbuf) {
  __shared__ int cur[NCLS];
  const int b = blockIdx.x;
  const int lane = threadIdx.x;
  if (lane < NCLS) cur[lane] = base_t[lane * NB + b];
  __syncthreads();
  const int s0 = b * CHUNK;
#pragma unroll
  for (int it = 0; it < CHUNK / 64; ++it) {
    int i = s0 + it * 64 + lane;
    int j = (i < M) ? label[i] : -1;
    unsigned long long mask = 0;
#pragma unroll
    for (int q = 0; q < NCLS; ++q) {
      unsigned long long mm = __ballot(j == q);
      if (j == q) mask = mm;
    }
    if (j >= 0) {
      int myoff = __popcll(mask & ((1ull << lane) - 1ull));
      int basec = cur[j];
      idxbuf[basec + myoff] = i;
      if (myoff == 0) cur[j] = basec + __popcll(mask);
    }
    __syncthreads();
  }
}

// ---------------- fp32 -> (hi, lo) bf16 split, RNE ----------------
__device__ inline void bsplit(float x, short& hi, short& lo) {
  unsigned u = __float_as_uint(x);
  unsigned rh = u + 0x7fffu + ((u >> 16) & 1u);
  unsigned short h = (unsigned short)(rh >> 16);
  float hf = __uint_as_float((unsigned)h << 16);
  float l = x - hf;  // exact
  unsigned ul = __float_as_uint(l);
  unsigned rl = ul + 0x7fffu + ((ul >> 16) & 1u);
  hi = (short)h;
  lo = (short)(rl >> 16);
}

// ---------------- per-class Gram via bf16-split MFMA ----------------
__global__ __launch_bounds__(512, 4) void cov_k(const float* __restrict__ Z,
                                                const int* __restrict__ idxbuf,
                                                const int* __restrict__ hist,
                                                const int* __restrict__ cstart,
                                                float* __restrict__ partials) {
  __shared__ __attribute__((aligned(16))) char arena[66048];

  const int b = blockIdx.x;
  const int cls = b / TSLOT, slot = b % TSLOT;
  const int t = threadIdx.x;
  const int lane = t & 63;
  const int w = t >> 6;
  const int r = w & 3;
  const int pass = w >> 2;
  const int col4 = t & 31;
  const int rg = t >> 5;

  const int mj = hist[cls];
  const int seg0 = cstart[cls];
  const int segend = seg0 + mj;
  const int nch = (mj + 63) / 64;

  f32x16 acc[4];
#pragma unroll
  for (int c = 0; c < 4; ++c)
#pragma unroll
    for (int i = 0; i < 16; ++i) acc[c][i] = 0.f;

  const int pcol = r * 32 + (lane & 31);
  const int h = lane >> 5;
  const int aswz = (pcol & 7) << 4;
  char* const bbase = arena + (pass ? 16384 : 0);

  float4 pv[4];
  {
    const int ch = slot;
    const int r0 = seg0 + ch * 64;
#pragma unroll
    for (int i = 0; i < 4; ++i) {
      int gr = r0 + rg * 4 + i;
      if (ch < nch && gr < segend) {
        int ridx = idxbuf[gr];
        pv[i] = *(const float4*)(Z + (size_t)ridx * D + col4 * 4);
      } else {
        pv[i] = make_float4(0.f, 0.f, 0.f, 0.f);
      }
    }
  }

  for (int ch = slot; ch < nch; ch += TSLOT) {
    __syncthreads();
    {
      float xs[4][4];
      xs[0][0] = pv[0].x; xs[0][1] = pv[0].y; xs[0][2] = pv[0].z; xs[0][3] = pv[0].w;
      xs[1][0] = pv[1].x; xs[1][1] = pv[1].y; xs[1][2] = pv[1].z; xs[1][3] = pv[1].w;
      xs[2][0] = pv[2].x; xs[2][1] = pv[2].y; xs[2][2] = pv[2].z; xs[2][3] = pv[2].w;
      xs[3][0] = pv[3].x; xs[3][1] = pv[3].y; xs[3][2] = pv[3].z; xs[3][3] = pv[3].w;
#pragma unroll
      for (int j = 0; j < 4; ++j) {
        short h0, h1, h2, h3, l0, l1, l2, l3;
        bsplit(xs[0][j], h0, l0);
        bsplit(xs[1][j], h1, l1);
        bsplit(xs[2][j], h2, l2);
        bsplit(xs[3][j], h3, l3);
        const int cc = col4 * 4 + j;
        const int off = cc * 128 + ((rg * 8) ^ ((cc & 7) << 4));
        *(short4*)(arena + off) = make_short4(h0, h1, h2, h3);
        *(short4*)(arena + 16384 + off) = make_short4(l0, l1, l2, l3);
      }
    }
    __syncthreads();
    {
      const int chn = ch + TSLOT;
      const int r0 = seg0 + chn * 64;
#pragma unroll
      for (int i = 0; i < 4; ++i) {
        int gr = r0 + rg * 4 + i;
        if (chn < nch && gr < segend) {
          int ridx = idxbuf[gr];
          pv[i] = *(const float4*)(Z + (size_t)ridx * D + col4 * 4);
        } else {
          pv[i] = make_float4(0.f, 0.f, 0.f, 0.f);
        }
      }
    }
#pragma unroll
    for (int kk = 0; kk < 4; ++kk) {
      const int koff = kk * 32 + h * 16;
      bf16x8 a = *(const bf16x8*)(arena + pcol * 128 + (koff ^ aswz));
#pragma unroll
      for (int c = 0; c < 4; ++c) {
        const int qcol = c * 32 + (lane & 31);
        bf16x8 bb = *(const bf16x8*)(bbase + qcol * 128 + (koff ^ ((qcol & 7) << 4)));
        acc[c] = __builtin_amdgcn_mfma_f32_32x32x16_bf16(a, bb, acc[c], 0, 0, 0);
      }
    }
  }

  __syncthreads();
  float* g2 = (float*)arena;
  if (pass == 1) {
#pragma unroll
    for (int c = 0; c < 4; ++c)
#pragma unroll
      for (int i = 0; i < 16; ++i) {
        int prow = r * 32 + (i & 3) + 8 * (i >> 2) + 4 * h;
        int qcol = c * 32 + (lane & 31);
        g2[prow * 129 + qcol] = acc[c][i];
      }
  }
  __syncthreads();
  if (pass == 0) {
    size_t base = (size_t)b * (D * D);
#pragma unroll
    for (int c = 0; c < 4; ++c)
#pragma unroll
      for (int i = 0; i < 16; ++i) {
        int prow = r * 32 + (i & 3) + 8 * (i >> 2) + 4 * h;
        int qcol = c * 32 + (lane & 31);
        float v = acc[c][i] + g2[prow * 129 + qcol] + g2[qcol * 129 + prow];
        partials[base + (size_t)prow * D + qcol] = v;
      }
  }
}

// ---------------- reduce partials -> 32 class covs + total cov ----------------
__global__ void reduce_k(const float* __restrict__ partials, float* __restrict__ covs) {
  int e = blockIdx.x * blockDim.x + threadIdx.x;
  double tot = 0.0;
  for (int j = 0; j < NCLS; ++j) {
    double s = 0.0;
    for (int t = 0; t < TSLOT; ++t)
      s += (double)partials[(size_t)(j * TSLOT + t) * (D * D) + e];
    covs[(size_t)j * (D * D) + e] = (float)s;
    tot += s;
  }
  covs[(size_t)NCLS * (D * D) + e] = (float)tot;
}

// ---------------- blocked Cholesky logdet ----------------
// One block (256 thr) per matrix, __launch_bounds__(256,1): no spills (33 blocks,
// occupancy irrelevant). Trailing update streams the ac operand to cap live regs
// at ~95 (acc 36 + ar 48 + acb 8).
template <int T>
__device__ void trailing_upd(float (*As)[132], int pbase, int tid) {
  const int ty = tid >> 4, tx = tid & 15;
  const int r0 = pbase + 32 + ty * T;
  const int c0 = pbase + 32 + tx * T;
  float acc[T][T];
#pragma unroll
  for (int a = 0; a < T; ++a)
#pragma unroll
    for (int b = 0; b < T; ++b) acc[a][b] = 0.f;
#pragma unroll
  for (int j0 = 0; j0 < 32; j0 += 8) {
    float ar[T][8];
#pragma unroll
    for (int a = 0; a < T; ++a) {
      float4 v0 = *(const float4*)&As[r0 + a][pbase + j0];
      float4 v1 = *(const float4*)&As[r0 + a][pbase + j0 + 4];
      ar[a][0] = v0.x; ar[a][1] = v0.y; ar[a][2] = v0.z; ar[a][3] = v0.w;
      ar[a][4] = v1.x; ar[a][5] = v1.y; ar[a][6] = v1.z; ar[a][7] = v1.w;
    }
#pragma unroll
    for (int b = 0; b < T; ++b) {
      float4 w0 = *(const float4*)&As[c0 + b][pbase + j0];
      float4 w1 = *(const float4*)&As[c0 + b][pbase + j0 + 4];
      float acb[8] = {w0.x, w0.y, w0.z, w0.w, w1.x, w1.y, w1.z, w1.w};
#pragma unroll
      for (int jj = 0; jj < 8; ++jj)
#pragma unroll
        for (int a = 0; a < T; ++a)
          acc[a][b] = fmaf(ar[a][jj], acb[jj], acc[a][b]);
    }
  }
#pragma unroll
  for (int a = 0; a < T; ++a)
#pragma unroll
    for (int b = 0; b < T; ++b)
      As[r0 + a][c0 + b] -= acc[a][b];
}

__global__ __launch_bounds__(256, 1) void chol_k(const float* __restrict__ covs,
                                                 const int* __restrict__ hist,
                                                 int Mtot, double* __restrict__ results) {
  __shared__ float As[128][132];
  __shared__ float Pl[32][36];
  __shared__ float invd[32];
  __shared__ double red[64];
  const int j = blockIdx.x;
  const float* A = covs + (size_t)j * (D * D);
  const int tid = threadIdx.x;
  const int lane = tid & 63;
  const int w = tid >> 6;

#pragma unroll
  for (int it = 0; it < 16; ++it) {
    int e = it * 1024 + tid * 4;
    int r = e >> 7, c = e & 127;
    *(float4*)&As[r][c] = *(const float4*)&A[e];
  }
  __syncthreads();

  double lda = 0.0;
#pragma unroll 1
  for (int p = 0; p < 4; ++p) {
    const int pbase = p * 32;
    // ---- diag factor (wave 0; lanes 32..63 mirror, contribute log(1)=0)
    if (w == 0) {
      const int l = lane & 31;
      float row[32];
#pragma unroll
      for (int c4 = 0; c4 < 8; ++c4) {
        float4 v = *(const float4*)&As[pbase + l][pbase + c4 * 4];
        row[c4 * 4 + 0] = v.x; row[c4 * 4 + 1] = v.y;
        row[c4 * 4 + 2] = v.z; row[c4 * 4 + 3] = v.w;
      }
      float mypiv = 1.f, myinv = 0.f;
#pragma unroll
      for (int k = 0; k < 32; ++k) {
        float piv = __shfl(row[k], k);
        float inv = rsqrtf(piv);
        inv = inv * (1.5f - 0.5f * piv * inv * inv);  // NR -> ~1ulp
        if (lane == k) { mypiv = piv; myinv = inv; }
        row[k] *= inv;  // row[k] := L[lane][k]
        float lrk = row[k];
#pragma unroll
        for (int c = k + 1; c < 32; ++c) {
          float lck = __shfl(row[k], c);  // = L[c][k]
          row[c] = fmaf(-lrk, lck, row[c]);
        }
      }
      if (lane < 32) {
#pragma unroll
        for (int c4 = 0; c4 < 8; ++c4)
          *(float4*)&Pl[lane][c4 * 4] =
              make_float4(row[c4 * 4], row[c4 * 4 + 1], row[c4 * 4 + 2], row[c4 * 4 + 3]);
        invd[lane] = myinv;
      }
      lda += log((double)mypiv);
    }
    __syncthreads();
    // ---- L21 solve: thread tid handles trailing row pbase+32+tid
    const int N2 = 96 - pbase;
    if (tid < N2) {
      const int R = pbase + 32 + tid;
      float x[32];
#pragma unroll
      for (int c4 = 0; c4 < 8; ++c4) {
        float4 v = *(const float4*)&As[R][pbase + c4 * 4];
        x[c4 * 4 + 0] = v.x; x[c4 * 4 + 1] = v.y;
        x[c4 * 4 + 2] = v.z; x[c4 * 4 + 3] = v.w;
      }
#pragma unroll
      for (int jj = 0; jj < 32; ++jj) {
        float s = x[jj];
        const float* pj = &Pl[jj][0];
        int i = 0;
#pragma unroll
        for (; i + 4 <= jj; i += 4) {
          float4 pv = *(const float4*)&pj[i];
          s = fmaf(-x[i], pv.x,
              fmaf(-x[i + 1], pv.y, fmaf(-x[i + 2], pv.z, fmaf(-x[i + 3], pv.w, s))));
        }
#pragma unroll
        for (; i < jj; ++i) s = fmaf(-x[i], pj[i], s);
        x[jj] = s * invd[jj];
      }
#pragma unroll
      for (int c4 = 0; c4 < 8; ++c4)
        *(float4*)&As[R][pbase + c4 * 4] =
            make_float4(x[c4 * 4], x[c4 * 4 + 1], x[c4 * 4 + 2], x[c4 * 4 + 3]);
    }
    __syncthreads();
    // ---- trailing update
    if (N2 == 96) trailing_upd<6>(As, pbase, tid);
    else if (N2 == 64) trailing_upd<4>(As, pbase, tid);
    else if (N2 == 32) trailing_upd<2>(As, pbase, tid);
    __syncthreads();
  }

  if (w == 0) red[lane] = lda;
  __syncthreads();
  if (tid == 0) {
    double lsum = 0.0;
    for (int i = 0; i < 64; ++i) lsum += red[i];
    if (j < NCLS) {
      int mj = hist[j];
      double res = 0.0;
      if (mj > 0) {
        double cj = (double)D / ((double)mj * 0.01);
        res = ((double)D * log(cj) + lsum) * (double)mj / (2.0 * (double)Mtot);
      }
      results[j] = res;
    } else {
      double c = (double)D / ((double)Mtot * 0.01);
      results[NCLS] = ((double)D * log(c) + lsum) * 0.5;
    }
  }
}

// ---------------- combine ----------------
__global__ void final_k(const double* __restrict__ results, float* __restrict__ out) {
  if (threadIdx.x == 0 && blockIdx.x == 0) {
    double s = 0.0;
    for (int j = 0; j < NCLS; ++j) s += results[j];
    out[0] = (float)(s - results[NCLS]);
  }
}

extern "C" void kernel_launch(void* const* d_in, const int* in_sizes, int n_in,
                              void* d_out, int out_size, void* d_ws, size_t ws_size,
                              hipStream_t stream) {
  const float* Z = (const float*)d_in[0];
  const int* label = (const int*)d_in[1];
  const int Mtot = in_sizes[1];
  float* out = (float*)d_out;
  const int NB = (Mtot + CHUNK - 1) / CHUNK;

  char* ws = (char*)d_ws;
  int* hist = (int*)(ws + 0);
  int* cstart = (int*)(ws + 256);
  double* results = (double*)(ws + 512);
  int* idxbuf = (int*)(ws + 1024);
  float* partials = (float*)(ws + 1024 + (size_t)Mtot * sizeof(int));
  float* covs = partials + (size_t)NCLS * TSLOT * D * D;
  int* blkhist_t = (int*)partials;  // aliased, dead before cov_k
  int* base_t = blkhist_t + (size_t)NCLS * NB;

  zero_k<<<1, 64, 0, stream>>>(hist);
  hist_blk_k<<<NB, 64, 0, stream>>>(label, Mtot, NB, blkhist_t, hist);
  prefix_k<<<1, 64, 0, stream>>>(hist, cstart);
  base_k<<<NCLS, 64, 0, stream>>>(blkhist_t, cstart, NB, base_t);
  scatter2_k<<<NB, 64, 0, stream>>>(label, Mtot, NB, base_t, idxbuf);
  cov_k<<<NCLS * TSLOT, 512, 0, stream>>>(Z, idxbuf, hist, cstart, partials);
  reduce_k<<<(D * D) / 256, 256, 0, stream>>>(partials, covs);
  chol_k<<<NCLS + 1, 256, 0, stream>>>(covs, hist, Mtot, results);
  final_k<<<1, 64, 0, stream>>>(results, out);
}

// Round 6
// 129.754 us; speedup vs baseline: 5.6851x; 1.0661x over previous
//
#include <hip/hip_runtime.h>
#include <math.h>

#define D 128
#define NCLS 32
#define TSLOT 16
#define CHUNK 256  // labels per sort block

typedef float f32x16 __attribute__((ext_vector_type(16)));
typedef short bf16x8 __attribute__((ext_vector_type(8)));

// ---------------- zero counters ----------------
__global__ void zero_k(int* hist) {
  int t = threadIdx.x;
  if (t < NCLS) hist[t] = 0;
}

// ---------------- per-block label histogram (+ global hist) ----------------
__global__ __launch_bounds__(64) void hist_blk_k(const int* __restrict__ label, int M,
                                                 int NB, int* __restrict__ blkhist_t,
                                                 int* __restrict__ hist) {
  __shared__ int h[NCLS];
  const int lane = threadIdx.x;
  const int b = blockIdx.x;
  if (lane < NCLS) h[lane] = 0;
  __syncthreads();
  const int s0 = b * CHUNK;
#pragma unroll
  for (int it = 0; it < CHUNK / 64; ++it) {
    int i = s0 + it * 64 + lane;
    if (i < M) atomicAdd(&h[label[i]], 1);
  }
  __syncthreads();
  if (lane < NCLS) {
    blkhist_t[lane * NB + b] = h[lane];
    atomicAdd(&hist[lane], h[lane]);
  }
}

// ---------------- exclusive prefix over classes ----------------
__global__ void prefix_k(const int* __restrict__ hist, int* __restrict__ cstart) {
  if (threadIdx.x == 0) {
    int run = 0;
    for (int j = 0; j < NCLS; ++j) { cstart[j] = run; run += hist[j]; }
    cstart[NCLS] = run;
  }
}

// ---------------- per-class scan over blocks: base_t[j][b] ----------------
__global__ __launch_bounds__(64) void base_k(const int* __restrict__ blkhist_t,
                                             const int* __restrict__ cstart, int NB,
                                             int* __restrict__ base_t) {
  const int j = blockIdx.x;
  const int lane = threadIdx.x;
  const int K = (NB + 63) / 64;
  int vals[32];
  int run = 0;
  for (int k = 0; k < K; ++k) {
    int b = lane * K + k;
    int v = (b < NB) ? blkhist_t[j * NB + b] : 0;
    vals[k] = v;
    run += v;
  }
  int incl = run;
  for (int off = 1; off < 64; off <<= 1) {
    int o = __shfl_up(incl, off);
    if (lane >= off) incl += o;
  }
  int pos = cstart[j] + (incl - run);
  for (int k = 0; k < K; ++k) {
    int b = lane * K + k;
    if (b < NB) base_t[j * NB + b] = pos;
    pos += vals[k];
  }
}

// ---------------- stable, atomic-free scatter (1 wave / block) ----------------
__global__ __launch_bounds__(64) void scatter2_k(const int* __restrict__ label, int M,
                                                 int NB, const int* __restrict__ base_t,
                                                 int* __restrict__ idxbuf) {
  __shared__ int cur[NCLS];
  const int b = blockIdx.x;
  const int lane = threadIdx.x;
  if (lane < NCLS) cur[lane] = base_t[lane * NB + b];
  __syncthreads();
  const int s0 = b * CHUNK;
#pragma unroll
  for (int it = 0; it < CHUNK / 64; ++it) {
    int i = s0 + it * 64 + lane;
    int j = (i < M) ? label[i] : -1;
    unsigned long long mask = 0;
#pragma unroll
    for (int q = 0; q < NCLS; ++q) {
      unsigned long long mm = __ballot(j == q);
      if (j == q) mask = mm;
    }
    if (j >= 0) {
      int myoff = __popcll(mask & ((1ull << lane) - 1ull));
      int basec = cur[j];
      idxbuf[basec + myoff] = i;
      if (myoff == 0) cur[j] = basec + __popcll(mask);
    }
    __syncthreads();
  }
}

// ---------------- fp32 -> (hi, lo) bf16 split, RNE ----------------
__device__ inline void bsplit(float x, short& hi, short& lo) {
  unsigned u = __float_as_uint(x);
  unsigned rh = u + 0x7fffu + ((u >> 16) & 1u);
  unsigned short h = (unsigned short)(rh >> 16);
  float hf = __uint_as_float((unsigned)h << 16);
  float l = x - hf;  // exact
  unsigned ul = __float_as_uint(l);
  unsigned rl = ul + 0x7fffu + ((ul >> 16) & 1u);
  hi = (short)h;
  lo = (short)(rl >> 16);
}

// ---------------- per-class Gram via bf16-split MFMA ----------------
__global__ __launch_bounds__(512, 4) void cov_k(const float* __restrict__ Z,
                                                const int* __restrict__ idxbuf,
                                                const int* __restrict__ hist,
                                                const int* __restrict__ cstart,
                                                float* __restrict__ partials) {
  __shared__ __attribute__((aligned(16))) char arena[66048];

  const int b = blockIdx.x;
  const int cls = b / TSLOT, slot = b % TSLOT;
  const int t = threadIdx.x;
  const int lane = t & 63;
  const int w = t >> 6;
  const int r = w & 3;
  const int pass = w >> 2;
  const int col4 = t & 31;
  const int rg = t >> 5;

  const int mj = hist[cls];
  const int seg0 = cstart[cls];
  const int segend = seg0 + mj;
  const int nch = (mj + 63) / 64;

  f32x16 acc[4];
#pragma unroll
  for (int c = 0; c < 4; ++c)
#pragma unroll
    for (int i = 0; i < 16; ++i) acc[c][i] = 0.f;

  const int pcol = r * 32 + (lane & 31);
  const int h = lane >> 5;
  const int aswz = (pcol & 7) << 4;
  char* const bbase = arena + (pass ? 16384 : 0);

  float4 pv[4];
  {
    const int ch = slot;
    const int r0 = seg0 + ch * 64;
#pragma unroll
    for (int i = 0; i < 4; ++i) {
      int gr = r0 + rg * 4 + i;
      if (ch < nch && gr < segend) {
        int ridx = idxbuf[gr];
        pv[i] = *(const float4*)(Z + (size_t)ridx * D + col4 * 4);
      } else {
        pv[i] = make_float4(0.f, 0.f, 0.f, 0.f);
      }
    }
  }

  for (int ch = slot; ch < nch; ch += TSLOT) {
    __syncthreads();
    {
      float xs[4][4];
      xs[0][0] = pv[0].x; xs[0][1] = pv[0].y; xs[0][2] = pv[0].z; xs[0][3] = pv[0].w;
      xs[1][0] = pv[1].x; xs[1][1] = pv[1].y; xs[1][2] = pv[1].z; xs[1][3] = pv[1].w;
      xs[2][0] = pv[2].x; xs[2][1] = pv[2].y; xs[2][2] = pv[2].z; xs[2][3] = pv[2].w;
      xs[3][0] = pv[3].x; xs[3][1] = pv[3].y; xs[3][2] = pv[3].z; xs[3][3] = pv[3].w;
#pragma unroll
      for (int j = 0; j < 4; ++j) {
        short h0, h1, h2, h3, l0, l1, l2, l3;
        bsplit(xs[0][j], h0, l0);
        bsplit(xs[1][j], h1, l1);
        bsplit(xs[2][j], h2, l2);
        bsplit(xs[3][j], h3, l3);
        const int cc = col4 * 4 + j;
        const int off = cc * 128 + ((rg * 8) ^ ((cc & 7) << 4));
        *(short4*)(arena + off) = make_short4(h0, h1, h2, h3);
        *(short4*)(arena + 16384 + off) = make_short4(l0, l1, l2, l3);
      }
    }
    __syncthreads();
    {
      const int chn = ch + TSLOT;
      const int r0 = seg0 + chn * 64;
#pragma unroll
      for (int i = 0; i < 4; ++i) {
        int gr = r0 + rg * 4 + i;
        if (chn < nch && gr < segend) {
          int ridx = idxbuf[gr];
          pv[i] = *(const float4*)(Z + (size_t)ridx * D + col4 * 4);
        } else {
          pv[i] = make_float4(0.f, 0.f, 0.f, 0.f);
        }
      }
    }
#pragma unroll
    for (int kk = 0; kk < 4; ++kk) {
      const int koff = kk * 32 + h * 16;
      bf16x8 a = *(const bf16x8*)(arena + pcol * 128 + (koff ^ aswz));
#pragma unroll
      for (int c = 0; c < 4; ++c) {
        const int qcol = c * 32 + (lane & 31);
        bf16x8 bb = *(const bf16x8*)(bbase + qcol * 128 + (koff ^ ((qcol & 7) << 4)));
        acc[c] = __builtin_amdgcn_mfma_f32_32x32x16_bf16(a, bb, acc[c], 0, 0, 0);
      }
    }
  }

  __syncthreads();
  float* g2 = (float*)arena;
  if (pass == 1) {
#pragma unroll
    for (int c = 0; c < 4; ++c)
#pragma unroll
      for (int i = 0; i < 16; ++i) {
        int prow = r * 32 + (i & 3) + 8 * (i >> 2) + 4 * h;
        int qcol = c * 32 + (lane & 31);
        g2[prow * 129 + qcol] = acc[c][i];
      }
  }
  __syncthreads();
  if (pass == 0) {
    size_t base = (size_t)b * (D * D);
#pragma unroll
    for (int c = 0; c < 4; ++c)
#pragma unroll
      for (int i = 0; i < 16; ++i) {
        int prow = r * 32 + (i & 3) + 8 * (i >> 2) + 4 * h;
        int qcol = c * 32 + (lane & 31);
        float v = acc[c][i] + g2[prow * 129 + qcol] + g2[qcol * 129 + prow];
        partials[base + (size_t)prow * D + qcol] = v;
      }
  }
}

// ---------------- reduce partials -> 32 class covs + total cov ----------------
__global__ void reduce_k(const float* __restrict__ partials, float* __restrict__ covs) {
  int e = blockIdx.x * blockDim.x + threadIdx.x;
  double tot = 0.0;
  for (int j = 0; j < NCLS; ++j) {
    double s = 0.0;
    for (int t = 0; t < TSLOT; ++t)
      s += (double)partials[(size_t)(j * TSLOT + t) * (D * D) + e];
    covs[(size_t)j * (D * D) + e] = (float)s;
    tot += s;
  }
  covs[(size_t)NCLS * (D * D) + e] = (float)tot;
}

// ---------------- blocked Cholesky logdet ----------------
// One block (256 thr) per matrix. Diag: wave 0, row-per-lane; per step ONE LDS
// round-trip (publish col-k element, batched b128 read-back) instead of 31
// serialized shuffles. Solve: i-outer right-looking substitution vs transposed
// L11 (PlT) -> ~1 fma chain per step. Trailing: register-tiled rank-32 update.
template <int T>
__device__ void trailing_upd(float (*As)[132], int pbase, int tid) {
  const int ty = tid >> 4, tx = tid & 15;
  const int r0 = pbase + 32 + ty * T;
  const int c0 = pbase + 32 + tx * T;
  float acc[T][T];
#pragma unroll
  for (int a = 0; a < T; ++a)
#pragma unroll
    for (int b = 0; b < T; ++b) acc[a][b] = 0.f;
#pragma unroll
  for (int j0 = 0; j0 < 32; j0 += 8) {
    float ar[T][8];
#pragma unroll
    for (int a = 0; a < T; ++a) {
      float4 v0 = *(const float4*)&As[r0 + a][pbase + j0];
      float4 v1 = *(const float4*)&As[r0 + a][pbase + j0 + 4];
      ar[a][0] = v0.x; ar[a][1] = v0.y; ar[a][2] = v0.z; ar[a][3] = v0.w;
      ar[a][4] = v1.x; ar[a][5] = v1.y; ar[a][6] = v1.z; ar[a][7] = v1.w;
    }
#pragma unroll
    for (int b = 0; b < T; ++b) {
      float4 w0 = *(const float4*)&As[c0 + b][pbase + j0];
      float4 w1 = *(const float4*)&As[c0 + b][pbase + j0 + 4];
      float acb[8] = {w0.x, w0.y, w0.z, w0.w, w1.x, w1.y, w1.z, w1.w};
#pragma unroll
      for (int jj = 0; jj < 8; ++jj)
#pragma unroll
        for (int a = 0; a < T; ++a)
          acc[a][b] = fmaf(ar[a][jj], acb[jj], acc[a][b]);
    }
  }
#pragma unroll
  for (int a = 0; a < T; ++a)
#pragma unroll
    for (int b = 0; b < T; ++b)
      As[r0 + a][c0 + b] -= acc[a][b];
}

__global__ __launch_bounds__(256, 1) void chol_k(const float* __restrict__ covs,
                                                 const int* __restrict__ hist,
                                                 int Mtot, double* __restrict__ results) {
  __shared__ float As[128][132];
  __shared__ float PlT[32][36];  // PlT[i][jj] = L11[jj][i]
  __shared__ float invd[32];
  __shared__ float colbuf[32];
  __shared__ double red[64];
  const int j = blockIdx.x;
  const float* A = covs + (size_t)j * (D * D);
  const int tid = threadIdx.x;
  const int lane = tid & 63;
  const int w = tid >> 6;

#pragma unroll
  for (int it = 0; it < 16; ++it) {
    int e = it * 1024 + tid * 4;
    int r = e >> 7, c = e & 127;
    *(float4*)&As[r][c] = *(const float4*)&A[e];
  }
  __syncthreads();

  double lda = 0.0;
#pragma unroll 1
  for (int p = 0; p < 4; ++p) {
    const int pbase = p * 32;
    // ---- diag factor (wave 0; lanes 32..63 mirror, never match lane==k)
    if (w == 0) {
      const int l = lane & 31;
      float row[32];
#pragma unroll
      for (int c4 = 0; c4 < 8; ++c4) {
        float4 v = *(const float4*)&As[pbase + l][pbase + c4 * 4];
        row[c4 * 4 + 0] = v.x; row[c4 * 4 + 1] = v.y;
        row[c4 * 4 + 2] = v.z; row[c4 * 4 + 3] = v.w;
      }
      float mypiv = 1.f, myinv = 0.f;
#pragma unroll
      for (int k = 0; k < 32; ++k) {
        colbuf[l] = row[k];  // publish raw col-k element (lane l+32 dups value)
        float cb[32];
#pragma unroll
        for (int q = 0; q < 8; ++q) {
          float4 v = *(const float4*)&colbuf[q * 4];  // uniform addr -> broadcast
          cb[q * 4 + 0] = v.x; cb[q * 4 + 1] = v.y;
          cb[q * 4 + 2] = v.z; cb[q * 4 + 3] = v.w;
        }
        float piv = cb[k];
        float inv = rsqrtf(piv);
        inv = inv * (1.5f - 0.5f * piv * inv * inv);  // NR -> ~1ulp
        if (lane == k) { mypiv = piv; myinv = inv; }
        float tmul = row[k] * (inv * inv);  // raw_l / piv
#pragma unroll
        for (int c = k + 1; c < 32; ++c)
          row[c] = fmaf(-tmul, cb[c], row[c]);  // -= L[l][k]*L[c][k]
        row[k] *= inv;                          // finalize L[l][k]
      }
      if (lane < 32) {
#pragma unroll
        for (int c = 0; c < 32; ++c) PlT[c][lane] = row[c];  // L11 transposed
        invd[lane] = myinv;
      }
      lda += log((double)mypiv);
    }
    __syncthreads();
    // ---- L21 solve: thread tid handles trailing row pbase+32+tid (i-outer)
    const int N2 = 96 - pbase;
    if (tid < N2) {
      const int R = pbase + 32 + tid;
      float s[32];
#pragma unroll
      for (int c4 = 0; c4 < 8; ++c4) {
        float4 v = *(const float4*)&As[R][pbase + c4 * 4];
        s[c4 * 4 + 0] = v.x; s[c4 * 4 + 1] = v.y;
        s[c4 * 4 + 2] = v.z; s[c4 * 4 + 3] = v.w;
      }
#pragma unroll
      for (int i = 0; i < 32; ++i) {
        float xi = s[i] * invd[i];
        s[i] = xi;
#pragma unroll
        for (int jj = i + 1; jj < 32; ++jj)
          s[jj] = fmaf(-xi, PlT[i][jj], s[jj]);
      }
#pragma unroll
      for (int c4 = 0; c4 < 8; ++c4)
        *(float4*)&As[R][pbase + c4 * 4] =
            make_float4(s[c4 * 4], s[c4 * 4 + 1], s[c4 * 4 + 2], s[c4 * 4 + 3]);
    }
    __syncthreads();
    // ---- trailing update
    if (N2 == 96) trailing_upd<6>(As, pbase, tid);
    else if (N2 == 64) trailing_upd<4>(As, pbase, tid);
    else if (N2 == 32) trailing_upd<2>(As, pbase, tid);
    __syncthreads();
  }

  if (w == 0) red[lane] = lda;
  __syncthreads();
  if (tid == 0) {
    double lsum = 0.0;
    for (int i = 0; i < 64; ++i) lsum += red[i];
    if (j < NCLS) {
      int mj = hist[j];
      double res = 0.0;
      if (mj > 0) {
        double cj = (double)D / ((double)mj * 0.01);
        res = ((double)D * log(cj) + lsum) * (double)mj / (2.0 * (double)Mtot);
      }
      results[j] = res;
    } else {
      double c = (double)D / ((double)Mtot * 0.01);
      results[NCLS] = ((double)D * log(c) + lsum) * 0.5;
    }
  }
}

// ---------------- combine ----------------
__global__ void final_k(const double* __restrict__ results, float* __restrict__ out) {
  if (threadIdx.x == 0 && blockIdx.x == 0) {
    double s = 0.0;
    for (int j = 0; j < NCLS; ++j) s += results[j];
    out[0] = (float)(s - results[NCLS]);
  }
}

extern "C" void kernel_launch(void* const* d_in, const int* in_sizes, int n_in,
                              void* d_out, int out_size, void* d_ws, size_t ws_size,
                              hipStream_t stream) {
  const float* Z = (const float*)d_in[0];
  const int* label = (const int*)d_in[1];
  const int Mtot = in_sizes[1];
  float* out = (float*)d_out;
  const int NB = (Mtot + CHUNK - 1) / CHUNK;

  char* ws = (char*)d_ws;
  int* hist = (int*)(ws + 0);
  int* cstart = (int*)(ws + 256);
  double* results = (double*)(ws + 512);
  int* idxbuf = (int*)(ws + 1024);
  float* partials = (float*)(ws + 1024 + (size_t)Mtot * sizeof(int));
  float* covs = partials + (size_t)NCLS * TSLOT * D * D;
  int* blkhist_t = (int*)partials;  // aliased, dead before cov_k
  int* base_t = blkhist_t + (size_t)NCLS * NB;

  zero_k<<<1, 64, 0, stream>>>(hist);
  hist_blk_k<<<NB, 64, 0, stream>>>(label, Mtot, NB, blkhist_t, hist);
  prefix_k<<<1, 64, 0, stream>>>(hist, cstart);
  base_k<<<NCLS, 64, 0, stream>>>(blkhist_t, cstart, NB, base_t);
  scatter2_k<<<NB, 64, 0, stream>>>(label, Mtot, NB, base_t, idxbuf);
  cov_k<<<NCLS * TSLOT, 512, 0, stream>>>(Z, idxbuf, hist, cstart, partials);
  reduce_k<<<(D * D) / 256, 256, 0, stream>>>(partials, covs);
  chol_k<<<NCLS + 1, 256, 0, stream>>>(covs, hist, Mtot, results);
  final_k<<<1, 64, 0, stream>>>(results, out);
}

// Round 7
// 129.176 us; speedup vs baseline: 5.7105x; 1.0045x over previous
//
#include <hip/hip_runtime.h>
#include <math.h>

#define D 128
#define NCLS 32
#define TSLOT 16
#define CHUNK 256  // labels per sort block

typedef float f32x16 __attribute__((ext_vector_type(16)));
typedef short bf16x8 __attribute__((ext_vector_type(8)));

// ---------------- zero counters ----------------
__global__ void zero_k(int* hist) {
  int t = threadIdx.x;
  if (t < NCLS) hist[t] = 0;
}

// ---------------- per-block label histogram (+ global hist) ----------------
__global__ __launch_bounds__(64) void hist_blk_k(const int* __restrict__ label, int M,
                                                 int NB, int* __restrict__ blkhist_t,
                                                 int* __restrict__ hist) {
  __shared__ int h[NCLS];
  const int lane = threadIdx.x;
  const int b = blockIdx.x;
  if (lane < NCLS) h[lane] = 0;
  __syncthreads();
  const int s0 = b * CHUNK;
#pragma unroll
  for (int it = 0; it < CHUNK / 64; ++it) {
    int i = s0 + it * 64 + lane;
    if (i < M) atomicAdd(&h[label[i]], 1);
  }
  __syncthreads();
  if (lane < NCLS) {
    blkhist_t[lane * NB + b] = h[lane];
    atomicAdd(&hist[lane], h[lane]);
  }
}

// ---------------- exclusive prefix over classes ----------------
__global__ void prefix_k(const int* __restrict__ hist, int* __restrict__ cstart) {
  if (threadIdx.x == 0) {
    int run = 0;
    for (int j = 0; j < NCLS; ++j) { cstart[j] = run; run += hist[j]; }
    cstart[NCLS] = run;
  }
}

// ---------------- per-class scan over blocks: base_t[j][b] ----------------
__global__ __launch_bounds__(64) void base_k(const int* __restrict__ blkhist_t,
                                             const int* __restrict__ cstart, int NB,
                                             int* __restrict__ base_t) {
  const int j = blockIdx.x;
  const int lane = threadIdx.x;
  const int K = (NB + 63) / 64;
  int vals[32];
  int run = 0;
  for (int k = 0; k < K; ++k) {
    int b = lane * K + k;
    int v = (b < NB) ? blkhist_t[j * NB + b] : 0;
    vals[k] = v;
    run += v;
  }
  int incl = run;
  for (int off = 1; off < 64; off <<= 1) {
    int o = __shfl_up(incl, off);
    if (lane >= off) incl += o;
  }
  int pos = cstart[j] + (incl - run);
  for (int k = 0; k < K; ++k) {
    int b = lane * K + k;
    if (b < NB) base_t[j * NB + b] = pos;
    pos += vals[k];
  }
}

// ---------------- stable, atomic-free scatter (1 wave / block) ----------------
__global__ __launch_bounds__(64) void scatter2_k(const int* __restrict__ label, int M,
                                                 int NB, const int* __restrict__ base_t,
                                                 int* __restrict__ idxbuf) {
  __shared__ int cur[NCLS];
  const int b = blockIdx.x;
  const int lane = threadIdx.x;
  if (lane < NCLS) cur[lane] = base_t[lane * NB + b];
  __syncthreads();
  const int s0 = b * CHUNK;
#pragma unroll
  for (int it = 0; it < CHUNK / 64; ++it) {
    int i = s0 + it * 64 + lane;
    int j = (i < M) ? label[i] : -1;
    unsigned long long mask = 0;
#pragma unroll
    for (int q = 0; q < NCLS; ++q) {
      unsigned long long mm = __ballot(j == q);
      if (j == q) mask = mm;
    }
    if (j >= 0) {
      int myoff = __popcll(mask & ((1ull << lane) - 1ull));
      int basec = cur[j];
      idxbuf[basec + myoff] = i;
      if (myoff == 0) cur[j] = basec + __popcll(mask);
    }
    __syncthreads();
  }
}

// ---------------- fp32 -> (hi, lo) bf16 split, RNE ----------------
__device__ inline void bsplit(float x, short& hi, short& lo) {
  unsigned u = __float_as_uint(x);
  unsigned rh = u + 0x7fffu + ((u >> 16) & 1u);
  unsigned short h = (unsigned short)(rh >> 16);
  float hf = __uint_as_float((unsigned)h << 16);
  float l = x - hf;  // exact
  unsigned ul = __float_as_uint(l);
  unsigned rl = ul + 0x7fffu + ((ul >> 16) & 1u);
  hi = (short)h;
  lo = (short)(rl >> 16);
}

// ---------------- per-class Gram via bf16-split MFMA ----------------
__global__ __launch_bounds__(512, 4) void cov_k(const float* __restrict__ Z,
                                                const int* __restrict__ idxbuf,
                                                const int* __restrict__ hist,
                                                const int* __restrict__ cstart,
                                                float* __restrict__ partials) {
  __shared__ __attribute__((aligned(16))) char arena[66048];

  const int b = blockIdx.x;
  const int cls = b / TSLOT, slot = b % TSLOT;
  const int t = threadIdx.x;
  const int lane = t & 63;
  const int w = t >> 6;
  const int r = w & 3;
  const int pass = w >> 2;
  const int col4 = t & 31;
  const int rg = t >> 5;

  const int mj = hist[cls];
  const int seg0 = cstart[cls];
  const int segend = seg0 + mj;
  const int nch = (mj + 63) / 64;

  f32x16 acc[4];
#pragma unroll
  for (int c = 0; c < 4; ++c)
#pragma unroll
    for (int i = 0; i < 16; ++i) acc[c][i] = 0.f;

  const int pcol = r * 32 + (lane & 31);
  const int h = lane >> 5;
  const int aswz = (pcol & 7) << 4;
  char* const bbase = arena + (pass ? 16384 : 0);

  float4 pv[4];
  {
    const int ch = slot;
    const int r0 = seg0 + ch * 64;
#pragma unroll
    for (int i = 0; i < 4; ++i) {
      int gr = r0 + rg * 4 + i;
      if (ch < nch && gr < segend) {
        int ridx = idxbuf[gr];
        pv[i] = *(const float4*)(Z + (size_t)ridx * D + col4 * 4);
      } else {
        pv[i] = make_float4(0.f, 0.f, 0.f, 0.f);
      }
    }
  }

  for (int ch = slot; ch < nch; ch += TSLOT) {
    __syncthreads();
    {
      float xs[4][4];
      xs[0][0] = pv[0].x; xs[0][1] = pv[0].y; xs[0][2] = pv[0].z; xs[0][3] = pv[0].w;
      xs[1][0] = pv[1].x; xs[1][1] = pv[1].y; xs[1][2] = pv[1].z; xs[1][3] = pv[1].w;
      xs[2][0] = pv[2].x; xs[2][1] = pv[2].y; xs[2][2] = pv[2].z; xs[2][3] = pv[2].w;
      xs[3][0] = pv[3].x; xs[3][1] = pv[3].y; xs[3][2] = pv[3].z; xs[3][3] = pv[3].w;
#pragma unroll
      for (int j = 0; j < 4; ++j) {
        short h0, h1, h2, h3, l0, l1, l2, l3;
        bsplit(xs[0][j], h0, l0);
        bsplit(xs[1][j], h1, l1);
        bsplit(xs[2][j], h2, l2);
        bsplit(xs[3][j], h3, l3);
        const int cc = col4 * 4 + j;
        const int off = cc * 128 + ((rg * 8) ^ ((cc & 7) << 4));
        *(short4*)(arena + off) = make_short4(h0, h1, h2, h3);
        *(short4*)(arena + 16384 + off) = make_short4(l0, l1, l2, l3);
      }
    }
    __syncthreads();
    {
      const int chn = ch + TSLOT;
      const int r0 = seg0 + chn * 64;
#pragma unroll
      for (int i = 0; i < 4; ++i) {
        int gr = r0 + rg * 4 + i;
        if (chn < nch && gr < segend) {
          int ridx = idxbuf[gr];
          pv[i] = *(const float4*)(Z + (size_t)ridx * D + col4 * 4);
        } else {
          pv[i] = make_float4(0.f, 0.f, 0.f, 0.f);
        }
      }
    }
#pragma unroll
    for (int kk = 0; kk < 4; ++kk) {
      const int koff = kk * 32 + h * 16;
      bf16x8 a = *(const bf16x8*)(arena + pcol * 128 + (koff ^ aswz));
#pragma unroll
      for (int c = 0; c < 4; ++c) {
        const int qcol = c * 32 + (lane & 31);
        bf16x8 bb = *(const bf16x8*)(bbase + qcol * 128 + (koff ^ ((qcol & 7) << 4)));
        acc[c] = __builtin_amdgcn_mfma_f32_32x32x16_bf16(a, bb, acc[c], 0, 0, 0);
      }
    }
  }

  __syncthreads();
  float* g2 = (float*)arena;
  if (pass == 1) {
#pragma unroll
    for (int c = 0; c < 4; ++c)
#pragma unroll
      for (int i = 0; i < 16; ++i) {
        int prow = r * 32 + (i & 3) + 8 * (i >> 2) + 4 * h;
        int qcol = c * 32 + (lane & 31);
        g2[prow * 129 + qcol] = acc[c][i];
      }
  }
  __syncthreads();
  if (pass == 0) {
    size_t base = (size_t)b * (D * D);
#pragma unroll
    for (int c = 0; c < 4; ++c)
#pragma unroll
      for (int i = 0; i < 16; ++i) {
        int prow = r * 32 + (i & 3) + 8 * (i >> 2) + 4 * h;
        int qcol = c * 32 + (lane & 31);
        float v = acc[c][i] + g2[prow * 129 + qcol] + g2[qcol * 129 + prow];
        partials[base + (size_t)prow * D + qcol] = v;
      }
  }
}

// ---------------- reduce partials -> 32 class covs + total cov ----------------
__global__ void reduce_k(const float* __restrict__ partials, float* __restrict__ covs) {
  int e = blockIdx.x * blockDim.x + threadIdx.x;
  double tot = 0.0;
  for (int j = 0; j < NCLS; ++j) {
    double s = 0.0;
    for (int t = 0; t < TSLOT; ++t)
      s += (double)partials[(size_t)(j * TSLOT + t) * (D * D) + e];
    covs[(size_t)j * (D * D) + e] = (float)s;
    tot += s;
  }
  covs[(size_t)NCLS * (D * D) + e] = (float)tot;
}

// ---------------- blocked Cholesky logdet ----------------
// One block (256 thr) per matrix. Diag: wave 0, row-per-lane; column broadcast
// via v_readlane -> SGPR (pure VALU, no LDS in the serial chain). Solve: i-outer
// substitution, invd preloaded to regs, PlT rows 16B-aligned uniform b128 reads.
// Trailing: register-tiled rank-32 update.
template <int T>
__device__ void trailing_upd(float (*As)[132], int pbase, int tid) {
  const int ty = tid >> 4, tx = tid & 15;
  const int r0 = pbase + 32 + ty * T;
  const int c0 = pbase + 32 + tx * T;
  float acc[T][T];
#pragma unroll
  for (int a = 0; a < T; ++a)
#pragma unroll
    for (int b = 0; b < T; ++b) acc[a][b] = 0.f;
#pragma unroll
  for (int j0 = 0; j0 < 32; j0 += 8) {
    float ar[T][8];
#pragma unroll
    for (int a = 0; a < T; ++a) {
      float4 v0 = *(const float4*)&As[r0 + a][pbase + j0];
      float4 v1 = *(const float4*)&As[r0 + a][pbase + j0 + 4];
      ar[a][0] = v0.x; ar[a][1] = v0.y; ar[a][2] = v0.z; ar[a][3] = v0.w;
      ar[a][4] = v1.x; ar[a][5] = v1.y; ar[a][6] = v1.z; ar[a][7] = v1.w;
    }
#pragma unroll
    for (int b = 0; b < T; ++b) {
      float4 w0 = *(const float4*)&As[c0 + b][pbase + j0];
      float4 w1 = *(const float4*)&As[c0 + b][pbase + j0 + 4];
      float acb[8] = {w0.x, w0.y, w0.z, w0.w, w1.x, w1.y, w1.z, w1.w};
#pragma unroll
      for (int jj = 0; jj < 8; ++jj)
#pragma unroll
        for (int a = 0; a < T; ++a)
          acc[a][b] = fmaf(ar[a][jj], acb[jj], acc[a][b]);
    }
  }
#pragma unroll
  for (int a = 0; a < T; ++a)
#pragma unroll
    for (int b = 0; b < T; ++b)
      As[r0 + a][c0 + b] -= acc[a][b];
}

__global__ __launch_bounds__(256, 1) void chol_k(const float* __restrict__ covs,
                                                 const int* __restrict__ hist,
                                                 int Mtot, double* __restrict__ results) {
  __shared__ float As[128][132];
  __shared__ float PlT[32][32];  // PlT[i][jj] = L11[jj][i]; rows 16B-aligned
  __shared__ float invd[32];
  __shared__ double red[64];
  const int j = blockIdx.x;
  const float* A = covs + (size_t)j * (D * D);
  const int tid = threadIdx.x;
  const int lane = tid & 63;
  const int w = tid >> 6;

#pragma unroll
  for (int it = 0; it < 16; ++it) {
    int e = it * 1024 + tid * 4;
    int r = e >> 7, c = e & 127;
    *(float4*)&As[r][c] = *(const float4*)&A[e];
  }
  __syncthreads();

  double lda = 0.0;
#pragma unroll 1
  for (int p = 0; p < 4; ++p) {
    const int pbase = p * 32;
    // ---- diag factor (wave 0; lanes 32..63 mirror, never match lane==k)
    if (w == 0) {
      const int l = lane & 31;
      float row[32];
#pragma unroll
      for (int c4 = 0; c4 < 8; ++c4) {
        float4 v = *(const float4*)&As[pbase + l][pbase + c4 * 4];
        row[c4 * 4 + 0] = v.x; row[c4 * 4 + 1] = v.y;
        row[c4 * 4 + 2] = v.z; row[c4 * 4 + 3] = v.w;
      }
      float mypiv = 1.f, myinv = 0.f;
#pragma unroll
      for (int k = 0; k < 32; ++k) {
        // pivot and raw column-k values via readlane (VALU->SGPR, no LDS)
        float piv = __int_as_float(__builtin_amdgcn_readlane(__float_as_int(row[k]), k));
        float inv = rsqrtf(piv);
        inv = inv * (1.5f - 0.5f * piv * inv * inv);  // NR -> ~1ulp
        if (lane == k) { mypiv = piv; myinv = inv; }
        float tmul = row[k] * (inv * inv);  // raw_l / piv
#pragma unroll
        for (int c = k + 1; c < 32; ++c) {
          float rawc = __int_as_float(__builtin_amdgcn_readlane(__float_as_int(row[k]), c));
          row[c] = fmaf(-tmul, rawc, row[c]);  // -= L[l][k]*L[c][k]
        }
        row[k] *= inv;  // finalize L[l][k]
      }
      if (lane < 32) {
#pragma unroll
        for (int c = 0; c < 32; ++c) PlT[c][lane] = row[c];  // L11 transposed
        invd[lane] = myinv;
      }
      lda += log((double)mypiv);
    }
    __syncthreads();
    // ---- L21 solve: thread tid handles trailing row pbase+32+tid (i-outer)
    const int N2 = 96 - pbase;
    if (tid < N2) {
      const int R = pbase + 32 + tid;
      float s[32], invr[32];
#pragma unroll
      for (int c4 = 0; c4 < 8; ++c4) {
        float4 v = *(const float4*)&As[R][pbase + c4 * 4];
        s[c4 * 4 + 0] = v.x; s[c4 * 4 + 1] = v.y;
        s[c4 * 4 + 2] = v.z; s[c4 * 4 + 3] = v.w;
        float4 u = *(const float4*)&invd[c4 * 4];
        invr[c4 * 4 + 0] = u.x; invr[c4 * 4 + 1] = u.y;
        invr[c4 * 4 + 2] = u.z; invr[c4 * 4 + 3] = u.w;
      }
#pragma unroll
      for (int i = 0; i < 32; ++i) {
        float xi = s[i] * invr[i];
        s[i] = xi;
        float pl[32];
#pragma unroll
        for (int q = 0; q < 8; ++q) {
          if (q * 4 + 3 > i) {  // only quads containing jj > i
            float4 v = *(const float4*)&PlT[i][q * 4];
            pl[q * 4 + 0] = v.x; pl[q * 4 + 1] = v.y;
            pl[q * 4 + 2] = v.z; pl[q * 4 + 3] = v.w;
          }
        }
#pragma unroll
        for (int jj = i + 1; jj < 32; ++jj)
          s[jj] = fmaf(-xi, pl[jj], s[jj]);
      }
#pragma unroll
      for (int c4 = 0; c4 < 8; ++c4)
        *(float4*)&As[R][pbase + c4 * 4] =
            make_float4(s[c4 * 4], s[c4 * 4 + 1], s[c4 * 4 + 2], s[c4 * 4 + 3]);
    }
    __syncthreads();
    // ---- trailing update
    if (N2 == 96) trailing_upd<6>(As, pbase, tid);
    else if (N2 == 64) trailing_upd<4>(As, pbase, tid);
    else if (N2 == 32) trailing_upd<2>(As, pbase, tid);
    __syncthreads();
  }

  if (w == 0) red[lane] = lda;
  __syncthreads();
  if (tid == 0) {
    double lsum = 0.0;
    for (int i = 0; i < 64; ++i) lsum += red[i];
    if (j < NCLS) {
      int mj = hist[j];
      double res = 0.0;
      if (mj > 0) {
        double cj = (double)D / ((double)mj * 0.01);
        res = ((double)D * log(cj) + lsum) * (double)mj / (2.0 * (double)Mtot);
      }
      results[j] = res;
    } else {
      double c = (double)D / ((double)Mtot * 0.01);
      results[NCLS] = ((double)D * log(c) + lsum) * 0.5;
    }
  }
}

// ---------------- combine ----------------
__global__ void final_k(const double* __restrict__ results, float* __restrict__ out) {
  if (threadIdx.x == 0 && blockIdx.x == 0) {
    double s = 0.0;
    for (int j = 0; j < NCLS; ++j) s += results[j];
    out[0] = (float)(s - results[NCLS]);
  }
}

extern "C" void kernel_launch(void* const* d_in, const int* in_sizes, int n_in,
                              void* d_out, int out_size, void* d_ws, size_t ws_size,
                              hipStream_t stream) {
  const float* Z = (const float*)d_in[0];
  const int* label = (const int*)d_in[1];
  const int Mtot = in_sizes[1];
  float* out = (float*)d_out;
  const int NB = (Mtot + CHUNK - 1) / CHUNK;

  char* ws = (char*)d_ws;
  int* hist = (int*)(ws + 0);
  int* cstart = (int*)(ws + 256);
  double* results = (double*)(ws + 512);
  int* idxbuf = (int*)(ws + 1024);
  float* partials = (float*)(ws + 1024 + (size_t)Mtot * sizeof(int));
  float* covs = partials + (size_t)NCLS * TSLOT * D * D;
  int* blkhist_t = (int*)partials;  // aliased, dead before cov_k
  int* base_t = blkhist_t + (size_t)NCLS * NB;

  zero_k<<<1, 64, 0, stream>>>(hist);
  hist_blk_k<<<NB, 64, 0, stream>>>(label, Mtot, NB, blkhist_t, hist);
  prefix_k<<<1, 64, 0, stream>>>(hist, cstart);
  base_k<<<NCLS, 64, 0, stream>>>(blkhist_t, cstart, NB, base_t);
  scatter2_k<<<NB, 64, 0, stream>>>(label, Mtot, NB, base_t, idxbuf);
  cov_k<<<NCLS * TSLOT, 512, 0, stream>>>(Z, idxbuf, hist, cstart, partials);
  reduce_k<<<(D * D) / 256, 256, 0, stream>>>(partials, covs);
  chol_k<<<NCLS + 1, 256, 0, stream>>>(covs, hist, Mtot, results);
  final_k<<<1, 64, 0, stream>>>(results, out);
}

// Round 8
// 126.321 us; speedup vs baseline: 5.8396x; 1.0226x over previous
//
#include <hip/hip_runtime.h>
#include <math.h>

#define D 128
#define NCLS 32
#define TSLOT 16
#define CHUNK 256  // labels per sort block

typedef float f32x16 __attribute__((ext_vector_type(16)));
typedef short bf16x8 __attribute__((ext_vector_type(8)));

// ---------------- zero counters ----------------
__global__ void zero_k(int* hist) {
  int t = threadIdx.x;
  if (t < NCLS) hist[t] = 0;
}

// ---------------- per-block label histogram (+ global hist) ----------------
__global__ __launch_bounds__(64) void hist_blk_k(const int* __restrict__ label, int M,
                                                 int NB, int* __restrict__ blkhist_t,
                                                 int* __restrict__ hist) {
  __shared__ int h[NCLS];
  const int lane = threadIdx.x;
  const int b = blockIdx.x;
  if (lane < NCLS) h[lane] = 0;
  __syncthreads();
  const int s0 = b * CHUNK;
#pragma unroll
  for (int it = 0; it < CHUNK / 64; ++it) {
    int i = s0 + it * 64 + lane;
    if (i < M) atomicAdd(&h[label[i]], 1);
  }
  __syncthreads();
  if (lane < NCLS) {
    blkhist_t[lane * NB + b] = h[lane];
    atomicAdd(&hist[lane], h[lane]);
  }
}

// ---------------- exclusive prefix over classes ----------------
__global__ void prefix_k(const int* __restrict__ hist, int* __restrict__ cstart) {
  if (threadIdx.x == 0) {
    int run = 0;
    for (int j = 0; j < NCLS; ++j) { cstart[j] = run; run += hist[j]; }
    cstart[NCLS] = run;
  }
}

// ---------------- per-class scan over blocks: base_t[j][b] ----------------
__global__ __launch_bounds__(64) void base_k(const int* __restrict__ blkhist_t,
                                             const int* __restrict__ cstart, int NB,
                                             int* __restrict__ base_t) {
  const int j = blockIdx.x;
  const int lane = threadIdx.x;
  const int K = (NB + 63) / 64;
  int vals[32];
  int run = 0;
  for (int k = 0; k < K; ++k) {
    int b = lane * K + k;
    int v = (b < NB) ? blkhist_t[j * NB + b] : 0;
    vals[k] = v;
    run += v;
  }
  int incl = run;
  for (int off = 1; off < 64; off <<= 1) {
    int o = __shfl_up(incl, off);
    if (lane >= off) incl += o;
  }
  int pos = cstart[j] + (incl - run);
  for (int k = 0; k < K; ++k) {
    int b = lane * K + k;
    if (b < NB) base_t[j * NB + b] = pos;
    pos += vals[k];
  }
}

// ---------------- stable, atomic-free scatter (1 wave / block) ----------------
__global__ __launch_bounds__(64) void scatter2_k(const int* __restrict__ label, int M,
                                                 int NB, const int* __restrict__ base_t,
                                                 int* __restrict__ idxbuf) {
  __shared__ int cur[NCLS];
  const int b = blockIdx.x;
  const int lane = threadIdx.x;
  if (lane < NCLS) cur[lane] = base_t[lane * NB + b];
  __syncthreads();
  const int s0 = b * CHUNK;
#pragma unroll
  for (int it = 0; it < CHUNK / 64; ++it) {
    int i = s0 + it * 64 + lane;
    int j = (i < M) ? label[i] : -1;
    unsigned long long mask = 0;
#pragma unroll
    for (int q = 0; q < NCLS; ++q) {
      unsigned long long mm = __ballot(j == q);
      if (j == q) mask = mm;
    }
    if (j >= 0) {
      int myoff = __popcll(mask & ((1ull << lane) - 1ull));
      int basec = cur[j];
      idxbuf[basec + myoff] = i;
      if (myoff == 0) cur[j] = basec + __popcll(mask);
    }
    __syncthreads();
  }
}

// ---------------- fp32 -> (hi, lo) bf16 split, RNE ----------------
__device__ inline void bsplit(float x, short& hi, short& lo) {
  unsigned u = __float_as_uint(x);
  unsigned rh = u + 0x7fffu + ((u >> 16) & 1u);
  unsigned short h = (unsigned short)(rh >> 16);
  float hf = __uint_as_float((unsigned)h << 16);
  float l = x - hf;  // exact
  unsigned ul = __float_as_uint(l);
  unsigned rl = ul + 0x7fffu + ((ul >> 16) & 1u);
  hi = (short)h;
  lo = (short)(rl >> 16);
}

// ---------------- per-class Gram via bf16-split MFMA ----------------
__global__ __launch_bounds__(512, 4) void cov_k(const float* __restrict__ Z,
                                                const int* __restrict__ idxbuf,
                                                const int* __restrict__ hist,
                                                const int* __restrict__ cstart,
                                                float* __restrict__ partials) {
  __shared__ __attribute__((aligned(16))) char arena[66048];

  const int b = blockIdx.x;
  const int cls = b / TSLOT, slot = b % TSLOT;
  const int t = threadIdx.x;
  const int lane = t & 63;
  const int w = t >> 6;
  const int r = w & 3;
  const int pass = w >> 2;
  const int col4 = t & 31;
  const int rg = t >> 5;

  const int mj = hist[cls];
  const int seg0 = cstart[cls];
  const int segend = seg0 + mj;
  const int nch = (mj + 63) / 64;

  f32x16 acc[4];
#pragma unroll
  for (int c = 0; c < 4; ++c)
#pragma unroll
    for (int i = 0; i < 16; ++i) acc[c][i] = 0.f;

  const int pcol = r * 32 + (lane & 31);
  const int h = lane >> 5;
  const int aswz = (pcol & 7) << 4;
  char* const bbase = arena + (pass ? 16384 : 0);

  float4 pv[4];
  {
    const int ch = slot;
    const int r0 = seg0 + ch * 64;
#pragma unroll
    for (int i = 0; i < 4; ++i) {
      int gr = r0 + rg * 4 + i;
      if (ch < nch && gr < segend) {
        int ridx = idxbuf[gr];
        pv[i] = *(const float4*)(Z + (size_t)ridx * D + col4 * 4);
      } else {
        pv[i] = make_float4(0.f, 0.f, 0.f, 0.f);
      }
    }
  }

  for (int ch = slot; ch < nch; ch += TSLOT) {
    __syncthreads();
    {
      float xs[4][4];
      xs[0][0] = pv[0].x; xs[0][1] = pv[0].y; xs[0][2] = pv[0].z; xs[0][3] = pv[0].w;
      xs[1][0] = pv[1].x; xs[1][1] = pv[1].y; xs[1][2] = pv[1].z; xs[1][3] = pv[1].w;
      xs[2][0] = pv[2].x; xs[2][1] = pv[2].y; xs[2][2] = pv[2].z; xs[2][3] = pv[2].w;
      xs[3][0] = pv[3].x; xs[3][1] = pv[3].y; xs[3][2] = pv[3].z; xs[3][3] = pv[3].w;
#pragma unroll
      for (int j = 0; j < 4; ++j) {
        short h0, h1, h2, h3, l0, l1, l2, l3;
        bsplit(xs[0][j], h0, l0);
        bsplit(xs[1][j], h1, l1);
        bsplit(xs[2][j], h2, l2);
        bsplit(xs[3][j], h3, l3);
        const int cc = col4 * 4 + j;
        const int off = cc * 128 + ((rg * 8) ^ ((cc & 7) << 4));
        *(short4*)(arena + off) = make_short4(h0, h1, h2, h3);
        *(short4*)(arena + 16384 + off) = make_short4(l0, l1, l2, l3);
      }
    }
    __syncthreads();
    {
      const int chn = ch + TSLOT;
      const int r0 = seg0 + chn * 64;
#pragma unroll
      for (int i = 0; i < 4; ++i) {
        int gr = r0 + rg * 4 + i;
        if (chn < nch && gr < segend) {
          int ridx = idxbuf[gr];
          pv[i] = *(const float4*)(Z + (size_t)ridx * D + col4 * 4);
        } else {
          pv[i] = make_float4(0.f, 0.f, 0.f, 0.f);
        }
      }
    }
#pragma unroll
    for (int kk = 0; kk < 4; ++kk) {
      const int koff = kk * 32 + h * 16;
      bf16x8 a = *(const bf16x8*)(arena + pcol * 128 + (koff ^ aswz));
#pragma unroll
      for (int c = 0; c < 4; ++c) {
        const int qcol = c * 32 + (lane & 31);
        bf16x8 bb = *(const bf16x8*)(bbase + qcol * 128 + (koff ^ ((qcol & 7) << 4)));
        acc[c] = __builtin_amdgcn_mfma_f32_32x32x16_bf16(a, bb, acc[c], 0, 0, 0);
      }
    }
  }

  __syncthreads();
  float* g2 = (float*)arena;
  if (pass == 1) {
#pragma unroll
    for (int c = 0; c < 4; ++c)
#pragma unroll
      for (int i = 0; i < 16; ++i) {
        int prow = r * 32 + (i & 3) + 8 * (i >> 2) + 4 * h;
        int qcol = c * 32 + (lane & 31);
        g2[prow * 129 + qcol] = acc[c][i];
      }
  }
  __syncthreads();
  if (pass == 0) {
    size_t base = (size_t)b * (D * D);
#pragma unroll
    for (int c = 0; c < 4; ++c)
#pragma unroll
      for (int i = 0; i < 16; ++i) {
        int prow = r * 32 + (i & 3) + 8 * (i >> 2) + 4 * h;
        int qcol = c * 32 + (lane & 31);
        float v = acc[c][i] + g2[prow * 129 + qcol] + g2[qcol * 129 + prow];
        partials[base + (size_t)prow * D + qcol] = v;
      }
  }
}

// ---------------- reduce partials -> 32 class covs + total cov ----------------
__global__ void reduce_k(const float* __restrict__ partials, float* __restrict__ covs) {
  int e = blockIdx.x * blockDim.x + threadIdx.x;
  double tot = 0.0;
  for (int j = 0; j < NCLS; ++j) {
    double s = 0.0;
    for (int t = 0; t < TSLOT; ++t)
      s += (double)partials[(size_t)(j * TSLOT + t) * (D * D) + e];
    covs[(size_t)j * (D * D) + e] = (float)s;
    tot += s;
  }
  covs[(size_t)NCLS * (D * D) + e] = (float)tot;
}

// ---------------- blocked Cholesky logdet ----------------
// One block (256 thr) per matrix. Diag: wave 0, LDS-broadcast (R6 form).
// Solve: i-outer substitution (R6 form), solved row kept in regs only.
// Trailing: A22 -= L21*L21^T on MFMA via hi/lo bf16 split (cov_k's verified
// Gram-layout trick: both operands read identical row-major k-slices).
__global__ __launch_bounds__(256, 1) void chol_k(const float* __restrict__ covs,
                                                 const int* __restrict__ hist,
                                                 int Mtot, double* __restrict__ results) {
  __shared__ float As[128][132];
  __shared__ float PlT[32][36];  // PlT[i][jj] = L11[jj][i]
  __shared__ float invd[32];
  __shared__ float colbuf[32];
  __shared__ double red[64];
  __shared__ __attribute__((aligned(16))) short Thi[96 * 40];  // 40-short (80B) pitch
  __shared__ __attribute__((aligned(16))) short Tlo[96 * 40];
  const int j = blockIdx.x;
  const float* A = covs + (size_t)j * (D * D);
  const int tid = threadIdx.x;
  const int lane = tid & 63;
  const int wv = tid >> 6;

#pragma unroll
  for (int it = 0; it < 16; ++it) {
    int e = it * 1024 + tid * 4;
    int r = e >> 7, c = e & 127;
    *(float4*)&As[r][c] = *(const float4*)&A[e];
  }
  __syncthreads();

  double lda = 0.0;
#pragma unroll 1
  for (int p = 0; p < 4; ++p) {
    const int pbase = p * 32;
    const int N2 = 96 - pbase;
    // ---- diag factor (wave 0; lanes 32..63 mirror, never match lane==k)
    if (wv == 0) {
      const int l = lane & 31;
      float row[32];
#pragma unroll
      for (int c4 = 0; c4 < 8; ++c4) {
        float4 v = *(const float4*)&As[pbase + l][pbase + c4 * 4];
        row[c4 * 4 + 0] = v.x; row[c4 * 4 + 1] = v.y;
        row[c4 * 4 + 2] = v.z; row[c4 * 4 + 3] = v.w;
      }
      float mypiv = 1.f, myinv = 0.f;
#pragma unroll
      for (int k = 0; k < 32; ++k) {
        colbuf[l] = row[k];  // publish raw col-k element
        float cb[32];
#pragma unroll
        for (int q = 0; q < 8; ++q) {
          float4 v = *(const float4*)&colbuf[q * 4];  // uniform addr -> broadcast
          cb[q * 4 + 0] = v.x; cb[q * 4 + 1] = v.y;
          cb[q * 4 + 2] = v.z; cb[q * 4 + 3] = v.w;
        }
        float piv = cb[k];
        float inv = rsqrtf(piv);
        inv = inv * (1.5f - 0.5f * piv * inv * inv);  // NR -> ~1ulp
        if (lane == k) { mypiv = piv; myinv = inv; }
        float tmul = row[k] * (inv * inv);  // raw_l / piv
#pragma unroll
        for (int c = k + 1; c < 32; ++c)
          row[c] = fmaf(-tmul, cb[c], row[c]);  // -= L[l][k]*L[c][k]
        row[k] *= inv;                          // finalize L[l][k]
      }
      if (lane < 32) {
#pragma unroll
        for (int c = 0; c < 32; ++c) PlT[c][lane] = row[c];  // L11 transposed
        invd[lane] = myinv;
      }
      lda += log((double)mypiv);
    }
    __syncthreads();
    // ---- L21 solve: thread tid handles trailing row pbase+32+tid (i-outer);
    // solved row stays in regs, emitted as hi/lo bf16 into Thi/Tlo.
    if (tid < N2) {
      const int R = pbase + 32 + tid;
      float s[32];
#pragma unroll
      for (int c4 = 0; c4 < 8; ++c4) {
        float4 v = *(const float4*)&As[R][pbase + c4 * 4];
        s[c4 * 4 + 0] = v.x; s[c4 * 4 + 1] = v.y;
        s[c4 * 4 + 2] = v.z; s[c4 * 4 + 3] = v.w;
      }
#pragma unroll
      for (int i = 0; i < 32; ++i) {
        float xi = s[i] * invd[i];
        s[i] = xi;
#pragma unroll
        for (int jj = i + 1; jj < 32; ++jj)
          s[jj] = fmaf(-xi, PlT[i][jj], s[jj]);
      }
      unsigned hp[16], lp[16];
#pragma unroll
      for (int q = 0; q < 16; ++q) {
        short ha, la, hb, lb;
        bsplit(s[2 * q], ha, la);
        bsplit(s[2 * q + 1], hb, lb);
        hp[q] = (unsigned)(unsigned short)ha | ((unsigned)(unsigned short)hb << 16);
        lp[q] = (unsigned)(unsigned short)la | ((unsigned)(unsigned short)lb << 16);
      }
#pragma unroll
      for (int q = 0; q < 4; ++q) {
        *(int4*)&Thi[tid * 40 + q * 8] =
            make_int4(hp[4 * q], hp[4 * q + 1], hp[4 * q + 2], hp[4 * q + 3]);
        *(int4*)&Tlo[tid * 40 + q * 8] =
            make_int4(lp[4 * q], lp[4 * q + 1], lp[4 * q + 2], lp[4 * q + 3]);
      }
    }
    __syncthreads();
    // ---- trailing update on MFMA: As22 -= L21 L21^T
    const int nstr = N2 >> 5;
    if (wv < nstr) {
      const int l31 = lane & 31;
      const int h = lane >> 5;
      const int arow = wv * 32 + l31;
#pragma unroll 1
      for (int ct = 0; ct < nstr; ++ct) {
        const int brow = ct * 32 + l31;
        f32x16 acc;
#pragma unroll
        for (int i = 0; i < 16; ++i) acc[i] = 0.f;
#pragma unroll
        for (int ks = 0; ks < 2; ++ks) {
          const int off = ks * 16 + h * 8;  // shorts
          bf16x8 ahi = *(const bf16x8*)&Thi[arow * 40 + off];
          bf16x8 alo = *(const bf16x8*)&Tlo[arow * 40 + off];
          bf16x8 bhi = *(const bf16x8*)&Thi[brow * 40 + off];
          bf16x8 blo = *(const bf16x8*)&Tlo[brow * 40 + off];
          acc = __builtin_amdgcn_mfma_f32_32x32x16_bf16(ahi, bhi, acc, 0, 0, 0);
          acc = __builtin_amdgcn_mfma_f32_32x32x16_bf16(ahi, blo, acc, 0, 0, 0);
          acc = __builtin_amdgcn_mfma_f32_32x32x16_bf16(alo, bhi, acc, 0, 0, 0);
        }
#pragma unroll
        for (int i = 0; i < 16; ++i) {
          int rr = pbase + 32 + wv * 32 + (i & 3) + 8 * (i >> 2) + 4 * h;
          int cc = pbase + 32 + ct * 32 + l31;
          As[rr][cc] -= acc[i];
        }
      }
    }
    __syncthreads();
  }

  if (wv == 0) red[lane] = lda;
  __syncthreads();
  if (tid == 0) {
    double lsum = 0.0;
    for (int i = 0; i < 64; ++i) lsum += red[i];
    if (j < NCLS) {
      int mj = hist[j];
      double res = 0.0;
      if (mj > 0) {
        double cj = (double)D / ((double)mj * 0.01);
        res = ((double)D * log(cj) + lsum) * (double)mj / (2.0 * (double)Mtot);
      }
      results[j] = res;
    } else {
      double c = (double)D / ((double)Mtot * 0.01);
      results[NCLS] = ((double)D * log(c) + lsum) * 0.5;
    }
  }
}

// ---------------- combine ----------------
__global__ void final_k(const double* __restrict__ results, float* __restrict__ out) {
  if (threadIdx.x == 0 && blockIdx.x == 0) {
    double s = 0.0;
    for (int j = 0; j < NCLS; ++j) s += results[j];
    out[0] = (float)(s - results[NCLS]);
  }
}

extern "C" void kernel_launch(void* const* d_in, const int* in_sizes, int n_in,
                              void* d_out, int out_size, void* d_ws, size_t ws_size,
                              hipStream_t stream) {
  const float* Z = (const float*)d_in[0];
  const int* label = (const int*)d_in[1];
  const int Mtot = in_sizes[1];
  float* out = (float*)d_out;
  const int NB = (Mtot + CHUNK - 1) / CHUNK;

  char* ws = (char*)d_ws;
  int* hist = (int*)(ws + 0);
  int* cstart = (int*)(ws + 256);
  double* results = (double*)(ws + 512);
  int* idxbuf = (int*)(ws + 1024);
  float* partials = (float*)(ws + 1024 + (size_t)Mtot * sizeof(int));
  float* covs = partials + (size_t)NCLS * TSLOT * D * D;
  int* blkhist_t = (int*)partials;  // aliased, dead before cov_k
  int* base_t = blkhist_t + (size_t)NCLS * NB;

  zero_k<<<1, 64, 0, stream>>>(hist);
  hist_blk_k<<<NB, 64, 0, stream>>>(label, Mtot, NB, blkhist_t, hist);
  prefix_k<<<1, 64, 0, stream>>>(hist, cstart);
  base_k<<<NCLS, 64, 0, stream>>>(blkhist_t, cstart, NB, base_t);
  scatter2_k<<<NB, 64, 0, stream>>>(label, Mtot, NB, base_t, idxbuf);
  cov_k<<<NCLS * TSLOT, 512, 0, stream>>>(Z, idxbuf, hist, cstart, partials);
  reduce_k<<<(D * D) / 256, 256, 0, stream>>>(partials, covs);
  chol_k<<<NCLS + 1, 256, 0, stream>>>(covs, hist, Mtot, results);
  final_k<<<1, 64, 0, stream>>>(results, out);
}

// Round 9
// 125.075 us; speedup vs baseline: 5.8977x; 1.0100x over previous
//
#include <hip/hip_runtime.h>
#include <math.h>

#define D 128
#define NCLS 32
#define TSLOT 16
#define CHUNK 256  // labels per sort block

typedef float f32x16 __attribute__((ext_vector_type(16)));
typedef short bf16x8 __attribute__((ext_vector_type(8)));

// ---------------- zero counters ----------------
__global__ void zero_k(int* hist) {
  int t = threadIdx.x;
  if (t < NCLS) hist[t] = 0;
}

// ---------------- per-block label histogram (+ global hist) ----------------
__global__ __launch_bounds__(64) void hist_blk_k(const int* __restrict__ label, int M,
                                                 int NB, int* __restrict__ blkhist_t,
                                                 int* __restrict__ hist) {
  __shared__ int h[NCLS];
  const int lane = threadIdx.x;
  const int b = blockIdx.x;
  if (lane < NCLS) h[lane] = 0;
  __syncthreads();
  const int s0 = b * CHUNK;
#pragma unroll
  for (int it = 0; it < CHUNK / 64; ++it) {
    int i = s0 + it * 64 + lane;
    if (i < M) atomicAdd(&h[label[i]], 1);
  }
  __syncthreads();
  if (lane < NCLS) {
    blkhist_t[lane * NB + b] = h[lane];
    atomicAdd(&hist[lane], h[lane]);
  }
}

// ---------------- exclusive prefix over classes ----------------
__global__ void prefix_k(const int* __restrict__ hist, int* __restrict__ cstart) {
  if (threadIdx.x == 0) {
    int run = 0;
    for (int j = 0; j < NCLS; ++j) { cstart[j] = run; run += hist[j]; }
    cstart[NCLS] = run;
  }
}

// ---------------- per-class scan over blocks: base_t[j][b] ----------------
__global__ __launch_bounds__(64) void base_k(const int* __restrict__ blkhist_t,
                                             const int* __restrict__ cstart, int NB,
                                             int* __restrict__ base_t) {
  const int j = blockIdx.x;
  const int lane = threadIdx.x;
  const int K = (NB + 63) / 64;
  int vals[32];
  int run = 0;
  for (int k = 0; k < K; ++k) {
    int b = lane * K + k;
    int v = (b < NB) ? blkhist_t[j * NB + b] : 0;
    vals[k] = v;
    run += v;
  }
  int incl = run;
  for (int off = 1; off < 64; off <<= 1) {
    int o = __shfl_up(incl, off);
    if (lane >= off) incl += o;
  }
  int pos = cstart[j] + (incl - run);
  for (int k = 0; k < K; ++k) {
    int b = lane * K + k;
    if (b < NB) base_t[j * NB + b] = pos;
    pos += vals[k];
  }
}

// ---------------- stable, atomic-free scatter (1 wave / block) ----------------
__global__ __launch_bounds__(64) void scatter2_k(const int* __restrict__ label, int M,
                                                 int NB, const int* __restrict__ base_t,
                                                 int* __restrict__ idxbuf) {
  __shared__ int cur[NCLS];
  const int b = blockIdx.x;
  const int lane = threadIdx.x;
  if (lane < NCLS) cur[lane] = base_t[lane * NB + b];
  __syncthreads();
  const int s0 = b * CHUNK;
#pragma unroll
  for (int it = 0; it < CHUNK / 64; ++it) {
    int i = s0 + it * 64 + lane;
    int j = (i < M) ? label[i] : -1;
    unsigned long long mask = 0;
#pragma unroll
    for (int q = 0; q < NCLS; ++q) {
      unsigned long long mm = __ballot(j == q);
      if (j == q) mask = mm;
    }
    if (j >= 0) {
      int myoff = __popcll(mask & ((1ull << lane) - 1ull));
      int basec = cur[j];
      idxbuf[basec + myoff] = i;
      if (myoff == 0) cur[j] = basec + __popcll(mask);
    }
    __syncthreads();
  }
}

// ---------------- fp32 -> (hi, lo) bf16 split, RNE ----------------
__device__ inline void bsplit(float x, short& hi, short& lo) {
  unsigned u = __float_as_uint(x);
  unsigned rh = u + 0x7fffu + ((u >> 16) & 1u);
  unsigned short h = (unsigned short)(rh >> 16);
  float hf = __uint_as_float((unsigned)h << 16);
  float l = x - hf;  // exact
  unsigned ul = __float_as_uint(l);
  unsigned rl = ul + 0x7fffu + ((ul >> 16) & 1u);
  hi = (short)h;
  lo = (short)(rl >> 16);
}

// ---------------- per-class Gram via bf16-split MFMA ----------------
// Fragment-ordered LDS: region(kk, c, h) = ((kk*4+c)*2+h), pitch 528 B (33x16B),
// 32 slots of 16 B per region, slot p = (n>>2) + 8*(n&3) for logical lane n.
// Reads: lane l reads slot p(l&31) in region (kk, c, l>>5) -> any bijection within
// a 512B window is conflict-free. Writes: thread (rg,col4), col cc=4*col4+j ->
// region c=col4>>3, p=(col4&7)+8j, byte + (rg&1)*8 -> exactly 4 dw/bank (min).
// Symmetrization fused: each wave owns 2 tiles (r, cp..cp+1) and accumulates
// hi.hi^T + hi.lo^T + lo.hi^T directly -> partial is symmetric-complete, no
// epilogue LDS round-trip.
__global__ __launch_bounds__(512, 4) void cov_k(const float* __restrict__ Z,
                                                const int* __restrict__ idxbuf,
                                                const int* __restrict__ hist,
                                                const int* __restrict__ cstart,
                                                float* __restrict__ partials) {
  __shared__ __attribute__((aligned(16))) char arena[2 * 16896];
  char* const ThiB = arena;
  char* const TloB = arena + 16896;

  const int b = blockIdx.x;
  const int cls = b / TSLOT, slot = b % TSLOT;
  const int t = threadIdx.x;
  const int lane = t & 63;
  const int w = t >> 6;
  const int r = w >> 1;        // A row-strip 0..3
  const int cp = (w & 1) * 2;  // B col-strip pair base: 0 or 2

  const int col4 = t & 31;  // stages cols 4*col4 .. +3
  const int rg = t >> 5;    // stages rows rg*4 .. +3 (k dim)
  // write base: region((rg>>2), col4>>3, (rg>>1)&1)*528 + (col4&7)*16 + (rg&1)*8
  const int wbase0 = (((rg >> 2) * 4 + (col4 >> 3)) * 2 + ((rg >> 1) & 1)) * 528 +
                     (col4 & 7) * 16 + (rg & 1) * 8;

  const int mj = hist[cls];
  const int seg0 = cstart[cls];
  const int segend = seg0 + mj;
  const int nch = (mj + 63) / 64;

  f32x16 acc[2];
#pragma unroll
  for (int u = 0; u < 2; ++u)
#pragma unroll
    for (int i = 0; i < 16; ++i) acc[u][i] = 0.f;

  // read-side per-lane constant offset
  const int n = lane & 31;
  const int poff = ((n >> 2) + 8 * (n & 3)) * 16 + (lane >> 5) * 528;

  float4 pv[4];
  {
    const int ch = slot;
    const int r0 = seg0 + ch * 64;
#pragma unroll
    for (int i = 0; i < 4; ++i) {
      int gr = r0 + rg * 4 + i;
      if (ch < nch && gr < segend) {
        int ridx = idxbuf[gr];
        pv[i] = *(const float4*)(Z + (size_t)ridx * D + col4 * 4);
      } else {
        pv[i] = make_float4(0.f, 0.f, 0.f, 0.f);
      }
    }
  }

  for (int ch = slot; ch < nch; ch += TSLOT) {
    __syncthreads();  // prior MFMA reads of arena done
    {
      float xs[4][4];
      xs[0][0] = pv[0].x; xs[0][1] = pv[0].y; xs[0][2] = pv[0].z; xs[0][3] = pv[0].w;
      xs[1][0] = pv[1].x; xs[1][1] = pv[1].y; xs[1][2] = pv[1].z; xs[1][3] = pv[1].w;
      xs[2][0] = pv[2].x; xs[2][1] = pv[2].y; xs[2][2] = pv[2].z; xs[2][3] = pv[2].w;
      xs[3][0] = pv[3].x; xs[3][1] = pv[3].y; xs[3][2] = pv[3].z; xs[3][3] = pv[3].w;
#pragma unroll
      for (int j = 0; j < 4; ++j) {
        short h0, h1, h2, h3, l0, l1, l2, l3;
        bsplit(xs[0][j], h0, l0);
        bsplit(xs[1][j], h1, l1);
        bsplit(xs[2][j], h2, l2);
        bsplit(xs[3][j], h3, l3);
        *(short4*)(ThiB + wbase0 + j * 128) = make_short4(h0, h1, h2, h3);
        *(short4*)(TloB + wbase0 + j * 128) = make_short4(l0, l1, l2, l3);
      }
    }
    __syncthreads();
    // prefetch next chunk (loads in flight under MFMA phase)
    {
      const int chn = ch + TSLOT;
      const int r0 = seg0 + chn * 64;
#pragma unroll
      for (int i = 0; i < 4; ++i) {
        int gr = r0 + rg * 4 + i;
        if (chn < nch && gr < segend) {
          int ridx = idxbuf[gr];
          pv[i] = *(const float4*)(Z + (size_t)ridx * D + col4 * 4);
        } else {
          pv[i] = make_float4(0.f, 0.f, 0.f, 0.f);
        }
      }
    }
    // MFMA: per kk, A strip r (hi+lo) x two B strips (hi+lo)
#pragma unroll
    for (int kk = 0; kk < 4; ++kk) {
      const int ab = (kk * 4 + r) * 1056 + poff;
      bf16x8 ahi = *(const bf16x8*)(ThiB + ab);
      bf16x8 alo = *(const bf16x8*)(TloB + ab);
#pragma unroll
      for (int u = 0; u < 2; ++u) {
        const int bb = (kk * 4 + cp + u) * 1056 + poff;
        bf16x8 bhi = *(const bf16x8*)(ThiB + bb);
        bf16x8 blo = *(const bf16x8*)(TloB + bb);
        acc[u] = __builtin_amdgcn_mfma_f32_32x32x16_bf16(ahi, bhi, acc[u], 0, 0, 0);
        acc[u] = __builtin_amdgcn_mfma_f32_32x32x16_bf16(ahi, blo, acc[u], 0, 0, 0);
        acc[u] = __builtin_amdgcn_mfma_f32_32x32x16_bf16(alo, bhi, acc[u], 0, 0, 0);
      }
    }
  }

  // epilogue: direct coalesced global write (partial already symmetric-complete)
  size_t base = (size_t)b * (D * D);
#pragma unroll
  for (int u = 0; u < 2; ++u)
#pragma unroll
    for (int i = 0; i < 16; ++i) {
      int prow = r * 32 + (i & 3) + 8 * (i >> 2) + 4 * (lane >> 5);
      int qcol = (cp + u) * 32 + (lane & 31);
      partials[base + (size_t)prow * D + qcol] = acc[u][i];
    }
}

// ---------------- reduce partials -> 32 class covs + total cov ----------------
__global__ void reduce_k(const float* __restrict__ partials, float* __restrict__ covs) {
  int e = blockIdx.x * blockDim.x + threadIdx.x;
  double tot = 0.0;
  for (int j = 0; j < NCLS; ++j) {
    double s = 0.0;
    for (int t = 0; t < TSLOT; ++t)
      s += (double)partials[(size_t)(j * TSLOT + t) * (D * D) + e];
    covs[(size_t)j * (D * D) + e] = (float)s;
    tot += s;
  }
  covs[(size_t)NCLS * (D * D) + e] = (float)tot;
}

// ---------------- blocked Cholesky logdet ----------------
// One block (256 thr) per matrix. Diag: wave 0, LDS-broadcast. Solve: i-outer
// substitution, solved row kept in regs. Trailing: MFMA via hi/lo bf16 split.
__global__ __launch_bounds__(256, 1) void chol_k(const float* __restrict__ covs,
                                                 const int* __restrict__ hist,
                                                 int Mtot, double* __restrict__ results) {
  __shared__ float As[128][132];
  __shared__ float PlT[32][36];  // PlT[i][jj] = L11[jj][i]
  __shared__ float invd[32];
  __shared__ float colbuf[32];
  __shared__ double red[64];
  __shared__ __attribute__((aligned(16))) short Thi[96 * 40];  // 40-short (80B) pitch
  __shared__ __attribute__((aligned(16))) short Tlo[96 * 40];
  const int j = blockIdx.x;
  const float* A = covs + (size_t)j * (D * D);
  const int tid = threadIdx.x;
  const int lane = tid & 63;
  const int wv = tid >> 6;

#pragma unroll
  for (int it = 0; it < 16; ++it) {
    int e = it * 1024 + tid * 4;
    int r = e >> 7, c = e & 127;
    *(float4*)&As[r][c] = *(const float4*)&A[e];
  }
  __syncthreads();

  double lda = 0.0;
#pragma unroll 1
  for (int p = 0; p < 4; ++p) {
    const int pbase = p * 32;
    const int N2 = 96 - pbase;
    // ---- diag factor (wave 0; lanes 32..63 mirror, never match lane==k)
    if (wv == 0) {
      const int l = lane & 31;
      float row[32];
#pragma unroll
      for (int c4 = 0; c4 < 8; ++c4) {
        float4 v = *(const float4*)&As[pbase + l][pbase + c4 * 4];
        row[c4 * 4 + 0] = v.x; row[c4 * 4 + 1] = v.y;
        row[c4 * 4 + 2] = v.z; row[c4 * 4 + 3] = v.w;
      }
      float mypiv = 1.f, myinv = 0.f;
#pragma unroll
      for (int k = 0; k < 32; ++k) {
        colbuf[l] = row[k];  // publish raw col-k element
        float cb[32];
#pragma unroll
        for (int q = 0; q < 8; ++q) {
          float4 v = *(const float4*)&colbuf[q * 4];  // uniform addr -> broadcast
          cb[q * 4 + 0] = v.x; cb[q * 4 + 1] = v.y;
          cb[q * 4 + 2] = v.z; cb[q * 4 + 3] = v.w;
        }
        float piv = cb[k];
        float inv = rsqrtf(piv);
        inv = inv * (1.5f - 0.5f * piv * inv * inv);  // NR -> ~1ulp
        if (lane == k) { mypiv = piv; myinv = inv; }
        float tmul = row[k] * (inv * inv);  // raw_l / piv
#pragma unroll
        for (int c = k + 1; c < 32; ++c)
          row[c] = fmaf(-tmul, cb[c], row[c]);  // -= L[l][k]*L[c][k]
        row[k] *= inv;                          // finalize L[l][k]
      }
      if (lane < 32) {
#pragma unroll
        for (int c = 0; c < 32; ++c) PlT[c][lane] = row[c];  // L11 transposed
        invd[lane] = myinv;
      }
      lda += log((double)mypiv);
    }
    __syncthreads();
    // ---- L21 solve: thread tid handles trailing row pbase+32+tid (i-outer);
    // solved row stays in regs, emitted as hi/lo bf16 into Thi/Tlo.
    if (tid < N2) {
      const int R = pbase + 32 + tid;
      float s[32];
#pragma unroll
      for (int c4 = 0; c4 < 8; ++c4) {
        float4 v = *(const float4*)&As[R][pbase + c4 * 4];
        s[c4 * 4 + 0] = v.x; s[c4 * 4 + 1] = v.y;
        s[c4 * 4 + 2] = v.z; s[c4 * 4 + 3] = v.w;
      }
#pragma unroll
      for (int i = 0; i < 32; ++i) {
        float xi = s[i] * invd[i];
        s[i] = xi;
#pragma unroll
        for (int jj = i + 1; jj < 32; ++jj)
          s[jj] = fmaf(-xi, PlT[i][jj], s[jj]);
      }
      unsigned hp[16], lp[16];
#pragma unroll
      for (int q = 0; q < 16; ++q) {
        short ha, la, hb, lb;
        bsplit(s[2 * q], ha, la);
        bsplit(s[2 * q + 1], hb, lb);
        hp[q] = (unsigned)(unsigned short)ha | ((unsigned)(unsigned short)hb << 16);
        lp[q] = (unsigned)(unsigned short)la | ((unsigned)(unsigned short)lb << 16);
      }
#pragma unroll
      for (int q = 0; q < 4; ++q) {
        *(int4*)&Thi[tid * 40 + q * 8] =
            make_int4(hp[4 * q], hp[4 * q + 1], hp[4 * q + 2], hp[4 * q + 3]);
        *(int4*)&Tlo[tid * 40 + q * 8] =
            make_int4(lp[4 * q], lp[4 * q + 1], lp[4 * q + 2], lp[4 * q + 3]);
      }
    }
    __syncthreads();
    // ---- trailing update on MFMA: As22 -= L21 L21^T
    const int nstr = N2 >> 5;
    if (wv < nstr) {
      const int l31 = lane & 31;
      const int h = lane >> 5;
      const int arow = wv * 32 + l31;
#pragma unroll 1
      for (int ct = 0; ct < nstr; ++ct) {
        const int brow = ct * 32 + l31;
        f32x16 acc;
#pragma unroll
        for (int i = 0; i < 16; ++i) acc[i] = 0.f;
#pragma unroll
        for (int ks = 0; ks < 2; ++ks) {
          const int off = ks * 16 + h * 8;  // shorts
          bf16x8 ahi = *(const bf16x8*)&Thi[arow * 40 + off];
          bf16x8 alo = *(const bf16x8*)&Tlo[arow * 40 + off];
          bf16x8 bhi = *(const bf16x8*)&Thi[brow * 40 + off];
          bf16x8 blo = *(const bf16x8*)&Tlo[brow * 40 + off];
          acc = __builtin_amdgcn_mfma_f32_32x32x16_bf16(ahi, bhi, acc, 0, 0, 0);
          acc = __builtin_amdgcn_mfma_f32_32x32x16_bf16(ahi, blo, acc, 0, 0, 0);
          acc = __builtin_amdgcn_mfma_f32_32x32x16_bf16(alo, bhi, acc, 0, 0, 0);
        }
#pragma unroll
        for (int i = 0; i < 16; ++i) {
          int rr = pbase + 32 + wv * 32 + (i & 3) + 8 * (i >> 2) + 4 * h;
          int cc = pbase + 32 + ct * 32 + l31;
          As[rr][cc] -= acc[i];
        }
      }
    }
    __syncthreads();
  }

  if (wv == 0) red[lane] = lda;
  __syncthreads();
  if (tid == 0) {
    double lsum = 0.0;
    for (int i = 0; i < 64; ++i) lsum += red[i];
    if (j < NCLS) {
      int mj = hist[j];
      double res = 0.0;
      if (mj > 0) {
        double cj = (double)D / ((double)mj * 0.01);
        res = ((double)D * log(cj) + lsum) * (double)mj / (2.0 * (double)Mtot);
      }
      results[j] = res;
    } else {
      double c = (double)D / ((double)Mtot * 0.01);
      results[NCLS] = ((double)D * log(c) + lsum) * 0.5;
    }
  }
}

// ---------------- combine ----------------
__global__ void final_k(const double* __restrict__ results, float* __restrict__ out) {
  if (threadIdx.x == 0 && blockIdx.x == 0) {
    double s = 0.0;
    for (int j = 0; j < NCLS; ++j) s += results[j];
    out[0] = (float)(s - results[NCLS]);
  }
}

extern "C" void kernel_launch(void* const* d_in, const int* in_sizes, int n_in,
                              void* d_out, int out_size, void* d_ws, size_t ws_size,
                              hipStream_t stream) {
  const float* Z = (const float*)d_in[0];
  const int* label = (const int*)d_in[1];
  const int Mtot = in_sizes[1];
  float* out = (float*)d_out;
  const int NB = (Mtot + CHUNK - 1) / CHUNK;

  char* ws = (char*)d_ws;
  int* hist = (int*)(ws + 0);
  int* cstart = (int*)(ws + 256);
  double* results = (double*)(ws + 512);
  int* idxbuf = (int*)(ws + 1024);
  float* partials = (float*)(ws + 1024 + (size_t)Mtot * sizeof(int));
  float* covs = partials + (size_t)NCLS * TSLOT * D * D;
  int* blkhist_t = (int*)partials;  // aliased, dead before cov_k
  int* base_t = blkhist_t + (size_t)NCLS * NB;

  zero_k<<<1, 64, 0, stream>>>(hist);
  hist_blk_k<<<NB, 64, 0, stream>>>(label, Mtot, NB, blkhist_t, hist);
  prefix_k<<<1, 64, 0, stream>>>(hist, cstart);
  base_k<<<NCLS, 64, 0, stream>>>(blkhist_t, cstart, NB, base_t);
  scatter2_k<<<NB, 64, 0, stream>>>(label, Mtot, NB, base_t, idxbuf);
  cov_k<<<NCLS * TSLOT, 512, 0, stream>>>(Z, idxbuf, hist, cstart, partials);
  reduce_k<<<(D * D) / 256, 256, 0, stream>>>(partials, covs);
  chol_k<<<NCLS + 1, 256, 0, stream>>>(covs, hist, Mtot, results);
  final_k<<<1, 64, 0, stream>>>(results, out);
}

// Round 10
// 122.718 us; speedup vs baseline: 6.0110x; 1.0192x over previous
//
#include <hip/hip_runtime.h>
#include <math.h>

#define D 128
#define NCLS 32
#define TSLOT 16
#define CHUNK 256  // labels per sort block

typedef float f32x16 __attribute__((ext_vector_type(16)));
typedef short bf16x8 __attribute__((ext_vector_type(8)));

// ---------------- zero counters ----------------
__global__ void zero_k(int* hist) {
  int t = threadIdx.x;
  if (t < NCLS) hist[t] = 0;
}

// ---------------- per-block label histogram (+ global hist) ----------------
__global__ __launch_bounds__(64) void hist_blk_k(const int* __restrict__ label, int M,
                                                 int NB, int* __restrict__ blkhist_t,
                                                 int* __restrict__ hist) {
  __shared__ int h[NCLS];
  const int lane = threadIdx.x;
  const int b = blockIdx.x;
  if (lane < NCLS) h[lane] = 0;
  __syncthreads();
  const int s0 = b * CHUNK;
#pragma unroll
  for (int it = 0; it < CHUNK / 64; ++it) {
    int i = s0 + it * 64 + lane;
    if (i < M) atomicAdd(&h[label[i]], 1);
  }
  __syncthreads();
  if (lane < NCLS) {
    blkhist_t[lane * NB + b] = h[lane];
    atomicAdd(&hist[lane], h[lane]);
  }
}

// ---------------- exclusive prefix over classes ----------------
__global__ void prefix_k(const int* __restrict__ hist, int* __restrict__ cstart) {
  if (threadIdx.x == 0) {
    int run = 0;
    for (int j = 0; j < NCLS; ++j) { cstart[j] = run; run += hist[j]; }
    cstart[NCLS] = run;
  }
}

// ---------------- per-class scan over blocks: base_t[j][b] ----------------
__global__ __launch_bounds__(64) void base_k(const int* __restrict__ blkhist_t,
                                             const int* __restrict__ cstart, int NB,
                                             int* __restrict__ base_t) {
  const int j = blockIdx.x;
  const int lane = threadIdx.x;
  const int K = (NB + 63) / 64;
  int vals[32];
  int run = 0;
  for (int k = 0; k < K; ++k) {
    int b = lane * K + k;
    int v = (b < NB) ? blkhist_t[j * NB + b] : 0;
    vals[k] = v;
    run += v;
  }
  int incl = run;
  for (int off = 1; off < 64; off <<= 1) {
    int o = __shfl_up(incl, off);
    if (lane >= off) incl += o;
  }
  int pos = cstart[j] + (incl - run);
  for (int k = 0; k < K; ++k) {
    int b = lane * K + k;
    if (b < NB) base_t[j * NB + b] = pos;
    pos += vals[k];
  }
}

// ---------------- stable, atomic-free scatter (1 wave / block) ----------------
__global__ __launch_bounds__(64) void scatter2_k(const int* __restrict__ label, int M,
                                                 int NB, const int* __restrict__ base_t,
                                                 int* __restrict__ idxbuf) {
  __shared__ int cur[NCLS];
  const int b = blockIdx.x;
  const int lane = threadIdx.x;
  if (lane < NCLS) cur[lane] = base_t[lane * NB + b];
  __syncthreads();
  const int s0 = b * CHUNK;
#pragma unroll
  for (int it = 0; it < CHUNK / 64; ++it) {
    int i = s0 + it * 64 + lane;
    int j = (i < M) ? label[i] : -1;
    unsigned long long mask = 0;
#pragma unroll
    for (int q = 0; q < NCLS; ++q) {
      unsigned long long mm = __ballot(j == q);
      if (j == q) mask = mm;
    }
    if (j >= 0) {
      int myoff = __popcll(mask & ((1ull << lane) - 1ull));
      int basec = cur[j];
      idxbuf[basec + myoff] = i;
      if (myoff == 0) cur[j] = basec + __popcll(mask);
    }
    __syncthreads();
  }
}

// ---------------- fp32 -> (hi, lo) bf16 split, RNE ----------------
__device__ inline void bsplit(float x, short& hi, short& lo) {
  unsigned u = __float_as_uint(x);
  unsigned rh = u + 0x7fffu + ((u >> 16) & 1u);
  unsigned short h = (unsigned short)(rh >> 16);
  float hf = __uint_as_float((unsigned)h << 16);
  float l = x - hf;  // exact
  unsigned ul = __float_as_uint(l);
  unsigned rl = ul + 0x7fffu + ((ul >> 16) & 1u);
  hi = (short)h;
  lo = (short)(rl >> 16);
}

// ---------------- per-class Gram via bf16-split MFMA ----------------
// Double-buffered fragment-ordered LDS (region pitch 528 B, slot bijection
// p=(n>>2)+8(n&3)); ONE barrier per 64-row chunk: staging chunk i (buf i&1)
// overlaps MFMA on buf (i-1)&1. K-loop computes two accumulators per tile:
//   HH = Hi.Hi^T  (ahi x bhi),  Q = Lo.Hi^T  (alo x bhi)
// -> only bhi read on the B side (4 reads + 4 MFMA per kk, was 6+6).
// Final G = HH + Q + Q^T via one 128x129 LDS transpose epilogue (exact same
// decomposition as before: HiHi + HiLo + LoHi; LoLo dropped ~2^-18).
__global__ __launch_bounds__(512, 4) void cov_k(const float* __restrict__ Z,
                                                const int* __restrict__ idxbuf,
                                                const int* __restrict__ hist,
                                                const int* __restrict__ cstart,
                                                float* __restrict__ partials) {
  __shared__ __attribute__((aligned(16))) char arena[2 * 33792];

  const int b = blockIdx.x;
  const int cls = b / TSLOT, slot = b % TSLOT;
  const int t = threadIdx.x;
  const int lane = t & 63;
  const int w = t >> 6;
  const int r = w >> 1;        // A row-strip 0..3
  const int cp = (w & 1) * 2;  // B col-strip pair base: 0 or 2

  const int col4 = t & 31;  // stages cols 4*col4 .. +3
  const int rg = t >> 5;    // stages rows rg*4 .. +3 (k dim)
  const int wbase0 = (((rg >> 2) * 4 + (col4 >> 3)) * 2 + ((rg >> 1) & 1)) * 528 +
                     (col4 & 7) * 16 + (rg & 1) * 8;

  const int mj = hist[cls];
  const int seg0 = cstart[cls];
  const int segend = seg0 + mj;
  const int nch = (mj + 63) / 64;

  f32x16 ahh[2], aq[2];
#pragma unroll
  for (int u = 0; u < 2; ++u)
#pragma unroll
    for (int i = 0; i < 16; ++i) { ahh[u][i] = 0.f; aq[u][i] = 0.f; }

  // read-side per-lane constant offset
  const int n = lane & 31;
  const int poff = ((n >> 2) + 8 * (n & 3)) * 16 + (lane >> 5) * 528;

  float4 pv[4];
  {
    const int ch = slot;
    const int r0 = seg0 + ch * 64;
#pragma unroll
    for (int i = 0; i < 4; ++i) {
      int gr = r0 + rg * 4 + i;
      if (ch < nch && gr < segend) {
        int ridx = idxbuf[gr];
        pv[i] = *(const float4*)(Z + (size_t)ridx * D + col4 * 4);
      } else {
        pv[i] = make_float4(0.f, 0.f, 0.f, 0.f);
      }
    }
  }

  int cur = 0;
#pragma unroll 1
  for (int ch = slot; ch < nch; ch += TSLOT) {
    char* const ThiB = arena + cur * 33792;
    char* const TloB = ThiB + 16896;
    // stage current chunk into buf[cur] (other waves may still MFMA buf[cur^1])
    {
      float xs[4][4];
      xs[0][0] = pv[0].x; xs[0][1] = pv[0].y; xs[0][2] = pv[0].z; xs[0][3] = pv[0].w;
      xs[1][0] = pv[1].x; xs[1][1] = pv[1].y; xs[1][2] = pv[1].z; xs[1][3] = pv[1].w;
      xs[2][0] = pv[2].x; xs[2][1] = pv[2].y; xs[2][2] = pv[2].z; xs[2][3] = pv[2].w;
      xs[3][0] = pv[3].x; xs[3][1] = pv[3].y; xs[3][2] = pv[3].z; xs[3][3] = pv[3].w;
#pragma unroll
      for (int j = 0; j < 4; ++j) {
        short h0, h1, h2, h3, l0, l1, l2, l3;
        bsplit(xs[0][j], h0, l0);
        bsplit(xs[1][j], h1, l1);
        bsplit(xs[2][j], h2, l2);
        bsplit(xs[3][j], h3, l3);
        *(short4*)(ThiB + wbase0 + j * 128) = make_short4(h0, h1, h2, h3);
        *(short4*)(TloB + wbase0 + j * 128) = make_short4(l0, l1, l2, l3);
      }
    }
    // issue next chunk's loads (land under this chunk's MFMA phase)
    {
      const int chn = ch + TSLOT;
      const int r0 = seg0 + chn * 64;
#pragma unroll
      for (int i = 0; i < 4; ++i) {
        int gr = r0 + rg * 4 + i;
        if (chn < nch && gr < segend) {
          int ridx = idxbuf[gr];
          pv[i] = *(const float4*)(Z + (size_t)ridx * D + col4 * 4);
        } else {
          pv[i] = make_float4(0.f, 0.f, 0.f, 0.f);
        }
      }
    }
    __syncthreads();  // buf[cur] staged by all waves
    // MFMA: per kk, A strip r (hi+lo) x two B strips (hi only)
#pragma unroll
    for (int kk = 0; kk < 4; ++kk) {
      const int ab = (kk * 4 + r) * 1056 + poff;
      bf16x8 ahi = *(const bf16x8*)(ThiB + ab);
      bf16x8 alo = *(const bf16x8*)(TloB + ab);
#pragma unroll
      for (int u = 0; u < 2; ++u) {
        const int bb = (kk * 4 + cp + u) * 1056 + poff;
        bf16x8 bhi = *(const bf16x8*)(ThiB + bb);
        ahh[u] = __builtin_amdgcn_mfma_f32_32x32x16_bf16(ahi, bhi, ahh[u], 0, 0, 0);
        aq[u] = __builtin_amdgcn_mfma_f32_32x32x16_bf16(alo, bhi, aq[u], 0, 0, 0);
      }
    }
    cur ^= 1;
  }

  // epilogue: G = HH + Q + Q^T via LDS transpose (overlays the dbuf arena)
  __syncthreads();  // all waves done with MFMA reads
  float* q2 = (float*)arena;
#pragma unroll
  for (int u = 0; u < 2; ++u)
#pragma unroll
    for (int i = 0; i < 16; ++i) {
      int prow = r * 32 + (i & 3) + 8 * (i >> 2) + 4 * (lane >> 5);
      int qcol = (cp + u) * 32 + (lane & 31);
      q2[prow * 129 + qcol] = aq[u][i];
    }
  __syncthreads();
  size_t base = (size_t)b * (D * D);
#pragma unroll
  for (int u = 0; u < 2; ++u)
#pragma unroll
    for (int i = 0; i < 16; ++i) {
      int prow = r * 32 + (i & 3) + 8 * (i >> 2) + 4 * (lane >> 5);
      int qcol = (cp + u) * 32 + (lane & 31);
      partials[base + (size_t)prow * D + qcol] = ahh[u][i] + aq[u][i] + q2[qcol * 129 + prow];
    }
}

// ---------------- reduce partials -> 32 class covs + total cov ----------------
__global__ void reduce_k(const float* __restrict__ partials, float* __restrict__ covs) {
  int e = blockIdx.x * blockDim.x + threadIdx.x;
  double tot = 0.0;
  for (int j = 0; j < NCLS; ++j) {
    double s = 0.0;
    for (int t = 0; t < TSLOT; ++t)
      s += (double)partials[(size_t)(j * TSLOT + t) * (D * D) + e];
    covs[(size_t)j * (D * D) + e] = (float)s;
    tot += s;
  }
  covs[(size_t)NCLS * (D * D) + e] = (float)tot;
}

// ---------------- blocked Cholesky logdet ----------------
// One block (256 thr) per matrix. Diag: wave 0, LDS-broadcast. Solve: i-outer
// substitution, solved row kept in regs. Trailing: MFMA via hi/lo bf16 split.
__global__ __launch_bounds__(256, 1) void chol_k(const float* __restrict__ covs,
                                                 const int* __restrict__ hist,
                                                 int Mtot, double* __restrict__ results) {
  __shared__ float As[128][132];
  __shared__ float PlT[32][36];  // PlT[i][jj] = L11[jj][i]
  __shared__ float invd[32];
  __shared__ float colbuf[32];
  __shared__ double red[64];
  __shared__ __attribute__((aligned(16))) short Thi[96 * 40];  // 40-short (80B) pitch
  __shared__ __attribute__((aligned(16))) short Tlo[96 * 40];
  const int j = blockIdx.x;
  const float* A = covs + (size_t)j * (D * D);
  const int tid = threadIdx.x;
  const int lane = tid & 63;
  const int wv = tid >> 6;

#pragma unroll
  for (int it = 0; it < 16; ++it) {
    int e = it * 1024 + tid * 4;
    int r = e >> 7, c = e & 127;
    *(float4*)&As[r][c] = *(const float4*)&A[e];
  }
  __syncthreads();

  double lda = 0.0;
#pragma unroll 1
  for (int p = 0; p < 4; ++p) {
    const int pbase = p * 32;
    const int N2 = 96 - pbase;
    // ---- diag factor (wave 0; lanes 32..63 mirror, never match lane==k)
    if (wv == 0) {
      const int l = lane & 31;
      float row[32];
#pragma unroll
      for (int c4 = 0; c4 < 8; ++c4) {
        float4 v = *(const float4*)&As[pbase + l][pbase + c4 * 4];
        row[c4 * 4 + 0] = v.x; row[c4 * 4 + 1] = v.y;
        row[c4 * 4 + 2] = v.z; row[c4 * 4 + 3] = v.w;
      }
      float mypiv = 1.f, myinv = 0.f;
#pragma unroll
      for (int k = 0; k < 32; ++k) {
        colbuf[l] = row[k];  // publish raw col-k element
        float cb[32];
#pragma unroll
        for (int q = 0; q < 8; ++q) {
          float4 v = *(const float4*)&colbuf[q * 4];  // uniform addr -> broadcast
          cb[q * 4 + 0] = v.x; cb[q * 4 + 1] = v.y;
          cb[q * 4 + 2] = v.z; cb[q * 4 + 3] = v.w;
        }
        float piv = cb[k];
        float inv = rsqrtf(piv);
        inv = inv * (1.5f - 0.5f * piv * inv * inv);  // NR -> ~1ulp
        if (lane == k) { mypiv = piv; myinv = inv; }
        float tmul = row[k] * (inv * inv);  // raw_l / piv
#pragma unroll
        for (int c = k + 1; c < 32; ++c)
          row[c] = fmaf(-tmul, cb[c], row[c]);  // -= L[l][k]*L[c][k]
        row[k] *= inv;                          // finalize L[l][k]
      }
      if (lane < 32) {
#pragma unroll
        for (int c = 0; c < 32; ++c) PlT[c][lane] = row[c];  // L11 transposed
        invd[lane] = myinv;
      }
      lda += log((double)mypiv);
    }
    __syncthreads();
    // ---- L21 solve: thread tid handles trailing row pbase+32+tid (i-outer);
    // solved row stays in regs, emitted as hi/lo bf16 into Thi/Tlo.
    if (tid < N2) {
      const int R = pbase + 32 + tid;
      float s[32];
#pragma unroll
      for (int c4 = 0; c4 < 8; ++c4) {
        float4 v = *(const float4*)&As[R][pbase + c4 * 4];
        s[c4 * 4 + 0] = v.x; s[c4 * 4 + 1] = v.y;
        s[c4 * 4 + 2] = v.z; s[c4 * 4 + 3] = v.w;
      }
#pragma unroll
      for (int i = 0; i < 32; ++i) {
        float xi = s[i] * invd[i];
        s[i] = xi;
#pragma unroll
        for (int jj = i + 1; jj < 32; ++jj)
          s[jj] = fmaf(-xi, PlT[i][jj], s[jj]);
      }
      unsigned hp[16], lp[16];
#pragma unroll
      for (int q = 0; q < 16; ++q) {
        short ha, la, hb, lb;
        bsplit(s[2 * q], ha, la);
        bsplit(s[2 * q + 1], hb, lb);
        hp[q] = (unsigned)(unsigned short)ha | ((unsigned)(unsigned short)hb << 16);
        lp[q] = (unsigned)(unsigned short)la | ((unsigned)(unsigned short)lb << 16);
      }
#pragma unroll
      for (int q = 0; q < 4; ++q) {
        *(int4*)&Thi[tid * 40 + q * 8] =
            make_int4(hp[4 * q], hp[4 * q + 1], hp[4 * q + 2], hp[4 * q + 3]);
        *(int4*)&Tlo[tid * 40 + q * 8] =
            make_int4(lp[4 * q], lp[4 * q + 1], lp[4 * q + 2], lp[4 * q + 3]);
      }
    }
    __syncthreads();
    // ---- trailing update on MFMA: As22 -= L21 L21^T
    const int nstr = N2 >> 5;
    if (wv < nstr) {
      const int l31 = lane & 31;
      const int h = lane >> 5;
      const int arow = wv * 32 + l31;
#pragma unroll 1
      for (int ct = 0; ct < nstr; ++ct) {
        const int brow = ct * 32 + l31;
        f32x16 acc;
#pragma unroll
        for (int i = 0; i < 16; ++i) acc[i] = 0.f;
#pragma unroll
        for (int ks = 0; ks < 2; ++ks) {
          const int off = ks * 16 + h * 8;  // shorts
          bf16x8 ahi = *(const bf16x8*)&Thi[arow * 40 + off];
          bf16x8 alo = *(const bf16x8*)&Tlo[arow * 40 + off];
          bf16x8 bhi = *(const bf16x8*)&Thi[brow * 40 + off];
          bf16x8 blo = *(const bf16x8*)&Tlo[brow * 40 + off];
          acc = __builtin_amdgcn_mfma_f32_32x32x16_bf16(ahi, bhi, acc, 0, 0, 0);
          acc = __builtin_amdgcn_mfma_f32_32x32x16_bf16(ahi, blo, acc, 0, 0, 0);
          acc = __builtin_amdgcn_mfma_f32_32x32x16_bf16(alo, bhi, acc, 0, 0, 0);
        }
#pragma unroll
        for (int i = 0; i < 16; ++i) {
          int rr = pbase + 32 + wv * 32 + (i & 3) + 8 * (i >> 2) + 4 * h;
          int cc = pbase + 32 + ct * 32 + l31;
          As[rr][cc] -= acc[i];
        }
      }
    }
    __syncthreads();
  }

  if (wv == 0) red[lane] = lda;
  __syncthreads();
  if (tid == 0) {
    double lsum = 0.0;
    for (int i = 0; i < 64; ++i) lsum += red[i];
    if (j < NCLS) {
      int mj = hist[j];
      double res = 0.0;
      if (mj > 0) {
        double cj = (double)D / ((double)mj * 0.01);
        res = ((double)D * log(cj) + lsum) * (double)mj / (2.0 * (double)Mtot);
      }
      results[j] = res;
    } else {
      double c = (double)D / ((double)Mtot * 0.01);
      results[NCLS] = ((double)D * log(c) + lsum) * 0.5;
    }
  }
}

// ---------------- combine ----------------
__global__ void final_k(const double* __restrict__ results, float* __restrict__ out) {
  if (threadIdx.x == 0 && blockIdx.x == 0) {
    double s = 0.0;
    for (int j = 0; j < NCLS; ++j) s += results[j];
    out[0] = (float)(s - results[NCLS]);
  }
}

extern "C" void kernel_launch(void* const* d_in, const int* in_sizes, int n_in,
                              void* d_out, int out_size, void* d_ws, size_t ws_size,
                              hipStream_t stream) {
  const float* Z = (const float*)d_in[0];
  const int* label = (const int*)d_in[1];
  const int Mtot = in_sizes[1];
  float* out = (float*)d_out;
  const int NB = (Mtot + CHUNK - 1) / CHUNK;

  char* ws = (char*)d_ws;
  int* hist = (int*)(ws + 0);
  int* cstart = (int*)(ws + 256);
  double* results = (double*)(ws + 512);
  int* idxbuf = (int*)(ws + 1024);
  float* partials = (float*)(ws + 1024 + (size_t)Mtot * sizeof(int));
  float* covs = partials + (size_t)NCLS * TSLOT * D * D;
  int* blkhist_t = (int*)partials;  // aliased, dead before cov_k
  int* base_t = blkhist_t + (size_t)NCLS * NB;

  zero_k<<<1, 64, 0, stream>>>(hist);
  hist_blk_k<<<NB, 64, 0, stream>>>(label, Mtot, NB, blkhist_t, hist);
  prefix_k<<<1, 64, 0, stream>>>(hist, cstart);
  base_k<<<NCLS, 64, 0, stream>>>(blkhist_t, cstart, NB, base_t);
  scatter2_k<<<NB, 64, 0, stream>>>(label, Mtot, NB, base_t, idxbuf);
  cov_k<<<NCLS * TSLOT, 512, 0, stream>>>(Z, idxbuf, hist, cstart, partials);
  reduce_k<<<(D * D) / 256, 256, 0, stream>>>(partials, covs);
  chol_k<<<NCLS + 1, 256, 0, stream>>>(covs, hist, Mtot, results);
  final_k<<<1, 64, 0, stream>>>(results, out);
}

// Round 11
// 118.371 us; speedup vs baseline: 6.2318x; 1.0367x over previous
//
#include <hip/hip_runtime.h>
#include <math.h>

#define D 128
#define NCLS 32
#define TSLOT 16
#define CHUNK 256  // labels per sort block

typedef float f32x16 __attribute__((ext_vector_type(16)));
typedef short bf16x8 __attribute__((ext_vector_type(8)));

// ---------------- zero counters ----------------
__global__ void zero_k(int* hist) {
  int t = threadIdx.x;
  if (t < NCLS) hist[t] = 0;
}

// ---------------- per-block label histogram (+ global hist) ----------------
__global__ __launch_bounds__(64) void hist_blk_k(const int* __restrict__ label, int M,
                                                 int NB, int* __restrict__ blkhist_t,
                                                 int* __restrict__ hist) {
  __shared__ int h[NCLS];
  const int lane = threadIdx.x;
  const int b = blockIdx.x;
  if (lane < NCLS) h[lane] = 0;
  __syncthreads();
  const int s0 = b * CHUNK;
#pragma unroll
  for (int it = 0; it < CHUNK / 64; ++it) {
    int i = s0 + it * 64 + lane;
    if (i < M) atomicAdd(&h[label[i]], 1);
  }
  __syncthreads();
  if (lane < NCLS) {
    blkhist_t[lane * NB + b] = h[lane];
    atomicAdd(&hist[lane], h[lane]);
  }
}

// ---------------- exclusive prefix over classes ----------------
__global__ void prefix_k(const int* __restrict__ hist, int* __restrict__ cstart) {
  if (threadIdx.x == 0) {
    int run = 0;
    for (int j = 0; j < NCLS; ++j) { cstart[j] = run; run += hist[j]; }
    cstart[NCLS] = run;
  }
}

// ---------------- per-class scan over blocks: base_t[j][b] ----------------
__global__ __launch_bounds__(64) void base_k(const int* __restrict__ blkhist_t,
                                             const int* __restrict__ cstart, int NB,
                                             int* __restrict__ base_t) {
  const int j = blockIdx.x;
  const int lane = threadIdx.x;
  const int K = (NB + 63) / 64;
  int vals[32];
  int run = 0;
  for (int k = 0; k < K; ++k) {
    int b = lane * K + k;
    int v = (b < NB) ? blkhist_t[j * NB + b] : 0;
    vals[k] = v;
    run += v;
  }
  int incl = run;
  for (int off = 1; off < 64; off <<= 1) {
    int o = __shfl_up(incl, off);
    if (lane >= off) incl += o;
  }
  int pos = cstart[j] + (incl - run);
  for (int k = 0; k < K; ++k) {
    int b = lane * K + k;
    if (b < NB) base_t[j * NB + b] = pos;
    pos += vals[k];
  }
}

// ---------------- stable, atomic-free scatter (1 wave / block) ----------------
__global__ __launch_bounds__(64) void scatter2_k(const int* __restrict__ label, int M,
                                                 int NB, const int* __restrict__ base_t,
                                                 int* __restrict__ idxbuf) {
  __shared__ int cur[NCLS];
  const int b = blockIdx.x;
  const int lane = threadIdx.x;
  if (lane < NCLS) cur[lane] = base_t[lane * NB + b];
  __syncthreads();
  const int s0 = b * CHUNK;
#pragma unroll
  for (int it = 0; it < CHUNK / 64; ++it) {
    int i = s0 + it * 64 + lane;
    int j = (i < M) ? label[i] : -1;
    unsigned long long mask = 0;
#pragma unroll
    for (int q = 0; q < NCLS; ++q) {
      unsigned long long mm = __ballot(j == q);
      if (j == q) mask = mm;
    }
    if (j >= 0) {
      int myoff = __popcll(mask & ((1ull << lane) - 1ull));
      int basec = cur[j];
      idxbuf[basec + myoff] = i;
      if (myoff == 0) cur[j] = basec + __popcll(mask);
    }
    __syncthreads();
  }
}

// ---------------- fp32 -> (hi, lo) bf16 split, RNE ----------------
__device__ inline void bsplit(float x, short& hi, short& lo) {
  unsigned u = __float_as_uint(x);
  unsigned rh = u + 0x7fffu + ((u >> 16) & 1u);
  unsigned short h = (unsigned short)(rh >> 16);
  float hf = __uint_as_float((unsigned)h << 16);
  float l = x - hf;  // exact
  unsigned ul = __float_as_uint(l);
  unsigned rl = ul + 0x7fffu + ((ul >> 16) & 1u);
  hi = (short)h;
  lo = (short)(rl >> 16);
}

// ---------------- per-class Gram via bf16-split MFMA ----------------
// 1024 threads (16 waves) per block -> 2 blocks/CU = 32 waves/CU (full wave
// occupancy). Each wave owns ONE 32x32 output tile (r = w>>2, cq = w&3) and
// accumulates the symmetric-complete hi.hi^T + hi.lo^T + lo.hi^T directly.
// Fragment-ordered LDS arena (33.8 KB, region pitch 528 B, slot bijection
// p=(n>>2)+8(n&3)). Pipeline per 64-row chunk: barrier(arena free) -> stage
// -> barrier(staged) -> issue Z(c+1) [idx already resident] + idx(c+2) -> MFMA.
// The idx->Z dependent chain is split across iterations; loads drain at the
// next barrier only after a full MFMA+stage phase of latency hiding.
__global__ __launch_bounds__(1024, 8) void cov_k(const float* __restrict__ Z,
                                                 const int* __restrict__ idxbuf,
                                                 const int* __restrict__ hist,
                                                 const int* __restrict__ cstart,
                                                 float* __restrict__ partials) {
  __shared__ __attribute__((aligned(16))) char arena[33792];
  char* const ThiB = arena;
  char* const TloB = arena + 16896;

  const int b = blockIdx.x;
  const int cls = b / TSLOT, slot = b % TSLOT;
  const int t = threadIdx.x;
  const int lane = t & 63;
  const int w = t >> 6;
  const int r = w >> 2;   // A row-strip 0..3
  const int cq = w & 3;   // B col-strip 0..3

  const int col4 = t & 31;  // stages cols 4*col4 .. +3
  const int rg = t >> 5;    // stages rows rg*2, rg*2+1 (k dim)
  // write base: region((rg>>3)*4 + (col4>>3), h=(rg>>2)&1)
  const int wbase = (((rg >> 3) * 4 + (col4 >> 3)) * 2 + ((rg >> 2) & 1)) * 528 +
                    (col4 & 7) * 16 + (rg & 3) * 4;

  const int mj = hist[cls];
  const int seg0 = cstart[cls];
  const int segend = seg0 + mj;
  const int nch = (mj + 63) / 64;

  f32x16 acc;
#pragma unroll
  for (int i = 0; i < 16; ++i) acc[i] = 0.f;

  // read-side per-lane constant offset
  const int n = lane & 31;
  const int poff = ((n >> 2) + 8 * (n & 3)) * 16 + (lane >> 5) * 528;

  float4 pv[2];
  int idxn0 = 0, idxn1 = 0;
  {
    // prologue: idx(c0) -> issue Z(c0) -> idx(c1)
    const int ch = slot;
    const int r0 = seg0 + ch * 64;
    int i0 = 0, i1 = 0;
    if (ch < nch) {
      int g0 = r0 + rg * 2, g1 = r0 + rg * 2 + 1;
      if (g0 < segend) i0 = idxbuf[g0];
      if (g1 < segend) i1 = idxbuf[g1];
      pv[0] = (g0 < segend) ? *(const float4*)(Z + (size_t)i0 * D + col4 * 4)
                            : make_float4(0.f, 0.f, 0.f, 0.f);
      pv[1] = (g1 < segend) ? *(const float4*)(Z + (size_t)i1 * D + col4 * 4)
                            : make_float4(0.f, 0.f, 0.f, 0.f);
    } else {
      pv[0] = make_float4(0.f, 0.f, 0.f, 0.f);
      pv[1] = make_float4(0.f, 0.f, 0.f, 0.f);
    }
    const int chn = ch + TSLOT;
    const int r1 = seg0 + chn * 64;
    if (chn < nch) {
      int g0 = r1 + rg * 2, g1 = r1 + rg * 2 + 1;
      if (g0 < segend) idxn0 = idxbuf[g0];
      if (g1 < segend) idxn1 = idxbuf[g1];
    }
  }

#pragma unroll 1
  for (int ch = slot; ch < nch; ch += TSLOT) {
    __syncthreads();  // arena free (prior MFMA done by all waves)
    // stage chunk ch (pv arrived)
    {
      float xs[2][4];
      xs[0][0] = pv[0].x; xs[0][1] = pv[0].y; xs[0][2] = pv[0].z; xs[0][3] = pv[0].w;
      xs[1][0] = pv[1].x; xs[1][1] = pv[1].y; xs[1][2] = pv[1].z; xs[1][3] = pv[1].w;
#pragma unroll
      for (int j = 0; j < 4; ++j) {
        short h0, l0, h1, l1;
        bsplit(xs[0][j], h0, l0);
        bsplit(xs[1][j], h1, l1);
        *(short2*)(ThiB + wbase + j * 128) = make_short2(h0, h1);
        *(short2*)(TloB + wbase + j * 128) = make_short2(l0, l1);
      }
    }
    __syncthreads();  // arena staged by all waves
    // issue Z(ch+1) using resident idx, then idx(ch+2); both hide under MFMA
    {
      const int chn = ch + TSLOT;
      const int r1 = seg0 + chn * 64;
      int g0 = r1 + rg * 2, g1 = r1 + rg * 2 + 1;
      bool v0 = (chn < nch) && (g0 < segend);
      bool v1 = (chn < nch) && (g1 < segend);
      pv[0] = v0 ? *(const float4*)(Z + (size_t)idxn0 * D + col4 * 4)
                 : make_float4(0.f, 0.f, 0.f, 0.f);
      pv[1] = v1 ? *(const float4*)(Z + (size_t)idxn1 * D + col4 * 4)
                 : make_float4(0.f, 0.f, 0.f, 0.f);
      const int chn2 = ch + 2 * TSLOT;
      const int r2 = seg0 + chn2 * 64;
      if (chn2 < nch) {
        int h0 = r2 + rg * 2, h1 = r2 + rg * 2 + 1;
        if (h0 < segend) idxn0 = idxbuf[h0];
        if (h1 < segend) idxn1 = idxbuf[h1];
      }
    }
    // MFMA: one 32x32 tile per wave, symmetric-complete accumulation
#pragma unroll
    for (int kk = 0; kk < 4; ++kk) {
      const int ab = (kk * 4 + r) * 1056 + poff;
      const int bb = (kk * 4 + cq) * 1056 + poff;
      bf16x8 ahi = *(const bf16x8*)(ThiB + ab);
      bf16x8 alo = *(const bf16x8*)(TloB + ab);
      bf16x8 bhi = *(const bf16x8*)(ThiB + bb);
      bf16x8 blo = *(const bf16x8*)(TloB + bb);
      acc = __builtin_amdgcn_mfma_f32_32x32x16_bf16(ahi, bhi, acc, 0, 0, 0);
      acc = __builtin_amdgcn_mfma_f32_32x32x16_bf16(ahi, blo, acc, 0, 0, 0);
      acc = __builtin_amdgcn_mfma_f32_32x32x16_bf16(alo, bhi, acc, 0, 0, 0);
    }
  }

  // epilogue: direct coalesced global write (partial already symmetric-complete)
  size_t base = (size_t)b * (D * D);
#pragma unroll
  for (int i = 0; i < 16; ++i) {
    int prow = r * 32 + (i & 3) + 8 * (i >> 2) + 4 * (lane >> 5);
    int qcol = cq * 32 + (lane & 31);
    partials[base + (size_t)prow * D + qcol] = acc[i];
  }
}

// ---------------- reduce partials -> 32 class covs + total cov ----------------
__global__ void reduce_k(const float* __restrict__ partials, float* __restrict__ covs) {
  int e = blockIdx.x * blockDim.x + threadIdx.x;
  double tot = 0.0;
  for (int j = 0; j < NCLS; ++j) {
    double s = 0.0;
    for (int t = 0; t < TSLOT; ++t)
      s += (double)partials[(size_t)(j * TSLOT + t) * (D * D) + e];
    covs[(size_t)j * (D * D) + e] = (float)s;
    tot += s;
  }
  covs[(size_t)NCLS * (D * D) + e] = (float)tot;
}

// ---------------- blocked Cholesky logdet ----------------
// One block (256 thr) per matrix. Diag: wave 0, LDS-broadcast. Solve: i-outer
// substitution, solved row kept in regs. Trailing: MFMA via hi/lo bf16 split.
__global__ __launch_bounds__(256, 1) void chol_k(const float* __restrict__ covs,
                                                 const int* __restrict__ hist,
                                                 int Mtot, double* __restrict__ results) {
  __shared__ float As[128][132];
  __shared__ float PlT[32][36];  // PlT[i][jj] = L11[jj][i]
  __shared__ float invd[32];
  __shared__ float colbuf[32];
  __shared__ double red[64];
  __shared__ __attribute__((aligned(16))) short Thi[96 * 40];  // 40-short (80B) pitch
  __shared__ __attribute__((aligned(16))) short Tlo[96 * 40];
  const int j = blockIdx.x;
  const float* A = covs + (size_t)j * (D * D);
  const int tid = threadIdx.x;
  const int lane = tid & 63;
  const int wv = tid >> 6;

#pragma unroll
  for (int it = 0; it < 16; ++it) {
    int e = it * 1024 + tid * 4;
    int r = e >> 7, c = e & 127;
    *(float4*)&As[r][c] = *(const float4*)&A[e];
  }
  __syncthreads();

  double lda = 0.0;
#pragma unroll 1
  for (int p = 0; p < 4; ++p) {
    const int pbase = p * 32;
    const int N2 = 96 - pbase;
    // ---- diag factor (wave 0; lanes 32..63 mirror, never match lane==k)
    if (wv == 0) {
      const int l = lane & 31;
      float row[32];
#pragma unroll
      for (int c4 = 0; c4 < 8; ++c4) {
        float4 v = *(const float4*)&As[pbase + l][pbase + c4 * 4];
        row[c4 * 4 + 0] = v.x; row[c4 * 4 + 1] = v.y;
        row[c4 * 4 + 2] = v.z; row[c4 * 4 + 3] = v.w;
      }
      float mypiv = 1.f, myinv = 0.f;
#pragma unroll
      for (int k = 0; k < 32; ++k) {
        colbuf[l] = row[k];  // publish raw col-k element
        float cb[32];
#pragma unroll
        for (int q = 0; q < 8; ++q) {
          float4 v = *(const float4*)&colbuf[q * 4];  // uniform addr -> broadcast
          cb[q * 4 + 0] = v.x; cb[q * 4 + 1] = v.y;
          cb[q * 4 + 2] = v.z; cb[q * 4 + 3] = v.w;
        }
        float piv = cb[k];
        float inv = rsqrtf(piv);
        inv = inv * (1.5f - 0.5f * piv * inv * inv);  // NR -> ~1ulp
        if (lane == k) { mypiv = piv; myinv = inv; }
        float tmul = row[k] * (inv * inv);  // raw_l / piv
#pragma unroll
        for (int c = k + 1; c < 32; ++c)
          row[c] = fmaf(-tmul, cb[c], row[c]);  // -= L[l][k]*L[c][k]
        row[k] *= inv;                          // finalize L[l][k]
      }
      if (lane < 32) {
#pragma unroll
        for (int c = 0; c < 32; ++c) PlT[c][lane] = row[c];  // L11 transposed
        invd[lane] = myinv;
      }
      lda += log((double)mypiv);
    }
    __syncthreads();
    // ---- L21 solve: thread tid handles trailing row pbase+32+tid (i-outer);
    // solved row stays in regs, emitted as hi/lo bf16 into Thi/Tlo.
    if (tid < N2) {
      const int R = pbase + 32 + tid;
      float s[32];
#pragma unroll
      for (int c4 = 0; c4 < 8; ++c4) {
        float4 v = *(const float4*)&As[R][pbase + c4 * 4];
        s[c4 * 4 + 0] = v.x; s[c4 * 4 + 1] = v.y;
        s[c4 * 4 + 2] = v.z; s[c4 * 4 + 3] = v.w;
      }
#pragma unroll
      for (int i = 0; i < 32; ++i) {
        float xi = s[i] * invd[i];
        s[i] = xi;
#pragma unroll
        for (int jj = i + 1; jj < 32; ++jj)
          s[jj] = fmaf(-xi, PlT[i][jj], s[jj]);
      }
      unsigned hp[16], lp[16];
#pragma unroll
      for (int q = 0; q < 16; ++q) {
        short ha, la, hb, lb;
        bsplit(s[2 * q], ha, la);
        bsplit(s[2 * q + 1], hb, lb);
        hp[q] = (unsigned)(unsigned short)ha | ((unsigned)(unsigned short)hb << 16);
        lp[q] = (unsigned)(unsigned short)la | ((unsigned)(unsigned short)lb << 16);
      }
#pragma unroll
      for (int q = 0; q < 4; ++q) {
        *(int4*)&Thi[tid * 40 + q * 8] =
            make_int4(hp[4 * q], hp[4 * q + 1], hp[4 * q + 2], hp[4 * q + 3]);
        *(int4*)&Tlo[tid * 40 + q * 8] =
            make_int4(lp[4 * q], lp[4 * q + 1], lp[4 * q + 2], lp[4 * q + 3]);
      }
    }
    __syncthreads();
    // ---- trailing update on MFMA: As22 -= L21 L21^T
    const int nstr = N2 >> 5;
    if (wv < nstr) {
      const int l31 = lane & 31;
      const int h = lane >> 5;
      const int arow = wv * 32 + l31;
#pragma unroll 1
      for (int ct = 0; ct < nstr; ++ct) {
        const int brow = ct * 32 + l31;
        f32x16 acc;
#pragma unroll
        for (int i = 0; i < 16; ++i) acc[i] = 0.f;
#pragma unroll
        for (int ks = 0; ks < 2; ++ks) {
          const int off = ks * 16 + h * 8;  // shorts
          bf16x8 ahi = *(const bf16x8*)&Thi[arow * 40 + off];
          bf16x8 alo = *(const bf16x8*)&Tlo[arow * 40 + off];
          bf16x8 bhi = *(const bf16x8*)&Thi[brow * 40 + off];
          bf16x8 blo = *(const bf16x8*)&Tlo[brow * 40 + off];
          acc = __builtin_amdgcn_mfma_f32_32x32x16_bf16(ahi, bhi, acc, 0, 0, 0);
          acc = __builtin_amdgcn_mfma_f32_32x32x16_bf16(ahi, blo, acc, 0, 0, 0);
          acc = __builtin_amdgcn_mfma_f32_32x32x16_bf16(alo, bhi, acc, 0, 0, 0);
        }
#pragma unroll
        for (int i = 0; i < 16; ++i) {
          int rr = pbase + 32 + wv * 32 + (i & 3) + 8 * (i >> 2) + 4 * h;
          int cc = pbase + 32 + ct * 32 + l31;
          As[rr][cc] -= acc[i];
        }
      }
    }
    __syncthreads();
  }

  if (wv == 0) red[lane] = lda;
  __syncthreads();
  if (tid == 0) {
    double lsum = 0.0;
    for (int i = 0; i < 64; ++i) lsum += red[i];
    if (j < NCLS) {
      int mj = hist[j];
      double res = 0.0;
      if (mj > 0) {
        double cj = (double)D / ((double)mj * 0.01);
        res = ((double)D * log(cj) + lsum) * (double)mj / (2.0 * (double)Mtot);
      }
      results[j] = res;
    } else {
      double c = (double)D / ((double)Mtot * 0.01);
      results[NCLS] = ((double)D * log(c) + lsum) * 0.5;
    }
  }
}

// ---------------- combine ----------------
__global__ void final_k(const double* __restrict__ results, float* __restrict__ out) {
  if (threadIdx.x == 0 && blockIdx.x == 0) {
    double s = 0.0;
    for (int j = 0; j < NCLS; ++j) s += results[j];
    out[0] = (float)(s - results[NCLS]);
  }
}

extern "C" void kernel_launch(void* const* d_in, const int* in_sizes, int n_in,
                              void* d_out, int out_size, void* d_ws, size_t ws_size,
                              hipStream_t stream) {
  const float* Z = (const float*)d_in[0];
  const int* label = (const int*)d_in[1];
  const int Mtot = in_sizes[1];
  float* out = (float*)d_out;
  const int NB = (Mtot + CHUNK - 1) / CHUNK;

  char* ws = (char*)d_ws;
  int* hist = (int*)(ws + 0);
  int* cstart = (int*)(ws + 256);
  double* results = (double*)(ws + 512);
  int* idxbuf = (int*)(ws + 1024);
  float* partials = (float*)(ws + 1024 + (size_t)Mtot * sizeof(int));
  float* covs = partials + (size_t)NCLS * TSLOT * D * D;
  int* blkhist_t = (int*)partials;  // aliased, dead before cov_k
  int* base_t = blkhist_t + (size_t)NCLS * NB;

  zero_k<<<1, 64, 0, stream>>>(hist);
  hist_blk_k<<<NB, 64, 0, stream>>>(label, Mtot, NB, blkhist_t, hist);
  prefix_k<<<1, 64, 0, stream>>>(hist, cstart);
  base_k<<<NCLS, 64, 0, stream>>>(blkhist_t, cstart, NB, base_t);
  scatter2_k<<<NB, 64, 0, stream>>>(label, Mtot, NB, base_t, idxbuf);
  cov_k<<<NCLS * TSLOT, 1024, 0, stream>>>(Z, idxbuf, hist, cstart, partials);
  reduce_k<<<(D * D) / 256, 256, 0, stream>>>(partials, covs);
  chol_k<<<NCLS + 1, 256, 0, stream>>>(covs, hist, Mtot, results);
  final_k<<<1, 64, 0, stream>>>(results, out);
}